// Round 1
// baseline (1993.319 us; speedup 1.0000x reference)
//
#include <hip/hip_runtime.h>
#include <math.h>

#define SQRT2 1.41421356237309515f

// ---------------- style: out[b][ci] = dot(z[b], mw[ci]) * scale + mb[ci]
__global__ __launch_bounds__(256) void style_kernel(
    const float* __restrict__ z, const float* __restrict__ mw,
    const float* __restrict__ mb, float* __restrict__ out,
    int B, int Ci, float scale) {
    int i = blockIdx.x * blockDim.x + threadIdx.x;
    if (i >= B * Ci) return;
    int b = i / Ci, ci = i % Ci;
    const float* zp = z + b * 512;
    const float* wp = mw + ci * 512;
    float acc = 0.f;
#pragma unroll 8
    for (int k = 0; k < 512; ++k) acc += zp[k] * wp[k];
    out[i] = acc * scale + mb[ci];
}

// ---------------- demod: one block per (b, co); reduce sum(w^2 * style^2)
__global__ __launch_bounds__(256) void demod_kernel(
    const float* __restrict__ w, const float* __restrict__ style,
    float* __restrict__ out, int Co, int Ci) {
    int co = blockIdx.x, b = blockIdx.y;
    const float* wp = w + (size_t)co * Ci * 9;
    const float* sp = style + b * Ci;
    float acc = 0.f;
    for (int idx = threadIdx.x; idx < Ci * 9; idx += 256) {
        int ci = idx / 9;
        float v = wp[idx];
        float s = sp[ci];
        acc += v * v * s * s;
    }
    __shared__ float red[4];
    for (int off = 32; off > 0; off >>= 1) acc += __shfl_down(acc, off, 64);
    if ((threadIdx.x & 63) == 0) red[threadIdx.x >> 6] = acc;
    __syncthreads();
    if (threadIdx.x == 0) {
        float t = red[0] + red[1] + red[2] + red[3];
        out[b * Co + co] = rsqrtf(t / (float)(Ci * 9) + 1e-8f);
    }
}

// ---------------- composite: h = fg + (1-mask)*bg   (B=16,C=256,S=32)
__global__ __launch_bounds__(256) void composite_kernel(
    const float* __restrict__ fg, const float* __restrict__ mask,
    const float* __restrict__ bg, float* __restrict__ out) {
    int i = blockIdx.x * blockDim.x + threadIdx.x;   // 16*256*1024 total
    int sp = i & 1023;
    int b = i >> 18;
    float m = mask[(b << 10) + sp];
    out[i] = fg[i] + (1.f - m) * bg[i];
}

// ---------------- direct 3x3 conv, pad 1, style folded on input,
// demod*acc + bias, leaky_relu*sqrt2. 32x32 spatial tile per block, COB co.
template <int COB>
__global__ __launch_bounds__(256) void conv3x3_kernel(
    const float* __restrict__ x, const float* __restrict__ w,
    const float* __restrict__ style, const float* __restrict__ demod,
    const float* __restrict__ bias, float* __restrict__ out,
    int Ci, int Co, int S, int tps) {
    __shared__ float xs[34 * 34];
    int tile = blockIdx.x;
    int cog = blockIdx.y;
    int b = blockIdx.z;
    int ty0 = (tile / tps) * 32, tx0 = (tile % tps) * 32;
    int tid = threadIdx.x;
    int py = tid >> 5, px = tid & 31;   // rows py+8i
    float acc[4][COB];
#pragma unroll
    for (int i = 0; i < 4; ++i)
#pragma unroll
        for (int c = 0; c < COB; ++c) acc[i][c] = 0.f;
    float sInv = rsqrtf((float)(Ci * 9));
    const float* wbase = w + (size_t)(cog * COB) * Ci * 9;
    for (int ci = 0; ci < Ci; ++ci) {
        float sc = style[b * Ci + ci] * sInv;
        const float* xp = x + (size_t)(b * Ci + ci) * S * S;
#pragma unroll
        for (int j = 0; j < 5; ++j) {
            int idx = tid + 256 * j;
            if (idx < 34 * 34) {
                int ly = idx / 34, lx = idx % 34;
                int gy = ty0 - 1 + ly, gx = tx0 - 1 + lx;
                float v = 0.f;
                if (gy >= 0 && gy < S && gx >= 0 && gx < S) v = xp[gy * S + gx];
                xs[idx] = v * sc;
            }
        }
        __syncthreads();
        const float* wp = wbase + ci * 9;
#pragma unroll
        for (int ky = 0; ky < 3; ++ky)
#pragma unroll
            for (int kx = 0; kx < 3; ++kx) {
                float wr[COB];
#pragma unroll
                for (int c = 0; c < COB; ++c) wr[c] = wp[c * Ci * 9 + ky * 3 + kx];
#pragma unroll
                for (int i = 0; i < 4; ++i) {
                    float xv = xs[(py + 8 * i + ky) * 34 + px + kx];
#pragma unroll
                    for (int c = 0; c < COB; ++c) acc[i][c] += xv * wr[c];
                }
            }
        __syncthreads();
    }
#pragma unroll
    for (int c = 0; c < COB; ++c) {
        int co = cog * COB + c;
        float d = demod[b * Co + co];
        float bi = bias[co];
#pragma unroll
        for (int i = 0; i < 4; ++i) {
            float v = acc[i][c] * d + bi;
            v = (v > 0.f ? v : 0.2f * v) * SQRT2;
            out[((size_t)(b * Co + co) * S + ty0 + py + 8 * i) * S + tx0 + px] = v;
        }
    }
}

// ---------------- transposed conv (lhs_dilation=2, pad2, flipped kernel):
// out[oy][ox] = sum_{r,s: oy-r even, ox-s even} w[r][s] * x[(oy-r)/2][(ox-s)/2]
// Each thread owns a 2x2 output quad -> exactly 9 taps/ci/co. Demod in epilogue.
__global__ __launch_bounds__(256) void upconv_kernel(
    const float* __restrict__ x, const float* __restrict__ w,
    const float* __restrict__ style, const float* __restrict__ demod,
    float* __restrict__ out, int Ci, int Co, int S, int tps) {
    __shared__ float xs[17 * 17];
    int So = 2 * S + 1;
    int tile = blockIdx.x;
    int cog = blockIdx.y, b = blockIdx.z;
    int oy0 = (tile / tps) * 32, ox0 = (tile % tps) * 32;
    int Y0 = oy0 >> 1, X0 = ox0 >> 1;
    int tid = threadIdx.x;
    int qy = tid >> 4, qx = tid & 15;
    float a00[8], a01[8], a10[8], a11[8];
#pragma unroll
    for (int c = 0; c < 8; ++c) { a00[c] = 0.f; a01[c] = 0.f; a10[c] = 0.f; a11[c] = 0.f; }
    float sInv = rsqrtf((float)(Ci * 9));
    const float* wbase = w + (size_t)(cog * 8) * Ci * 9;
    for (int ci = 0; ci < Ci; ++ci) {
        float sc = style[b * Ci + ci] * sInv;
        const float* xp = x + (size_t)(b * Ci + ci) * S * S;
#pragma unroll
        for (int j = 0; j < 2; ++j) {
            int idx = tid + 256 * j;
            if (idx < 17 * 17) {
                int ly = idx / 17, lx = idx % 17;
                int gy = Y0 - 1 + ly, gx = X0 - 1 + lx;
                float v = 0.f;
                if (gy >= 0 && gy < S && gx >= 0 && gx < S) v = xp[gy * S + gx];
                xs[idx] = v * sc;
            }
        }
        __syncthreads();
        float xa = xs[(qy + 1) * 17 + qx + 1];  // x[Y][X]
        float xb = xs[(qy + 1) * 17 + qx];      // x[Y][X-1]
        float xc = xs[qy * 17 + qx + 1];        // x[Y-1][X]
        float xd = xs[qy * 17 + qx];            // x[Y-1][X-1]
        const float* wp = wbase + ci * 9;
#pragma unroll
        for (int c = 0; c < 8; ++c) {
            const float* wc = wp + (size_t)c * Ci * 9;
            float w00 = wc[0], w01 = wc[1], w02 = wc[2];
            float w10 = wc[3], w11 = wc[4], w12 = wc[5];
            float w20 = wc[6], w21 = wc[7], w22 = wc[8];
            a00[c] += w00 * xa + w02 * xb + w20 * xc + w22 * xd;
            a01[c] += w01 * xa + w21 * xc;
            a10[c] += w10 * xa + w12 * xb;
            a11[c] += w11 * xa;
        }
        __syncthreads();
    }
    int oy = oy0 + 2 * qy, ox = ox0 + 2 * qx;
#pragma unroll
    for (int c = 0; c < 8; ++c) {
        int co = cog * 8 + c;
        float d = demod[b * Co + co];
        float* op = out + (size_t)(b * Co + co) * So * So;
        if (oy < So) {
            if (ox < So) op[oy * So + ox] = a00[c] * d;
            if (ox + 1 < So) op[oy * So + ox + 1] = a01[c] * d;
        }
        if (oy + 1 < So) {
            if (ox < So) op[(oy + 1) * So + ox] = a10[c] * d;
            if (ox + 1 < So) op[(oy + 1) * So + ox + 1] = a11[c] * d;
        }
    }
}

// ---------------- 4x4 blur (pad 1) on (2S+1) -> 2S, then bias + lrelu*sqrt2
__global__ __launch_bounds__(256) void blur_bias_act_kernel(
    const float* __restrict__ up, const float* __restrict__ bias,
    float* __restrict__ out, int C, int S2, int total) {
    int i = blockIdx.x * blockDim.x + threadIdx.x;
    if (i >= total) return;
    int Si = S2 + 1;
    int xo = i % S2;
    int t = i / S2;
    int yo = t % S2;
    int bc = t / S2;
    int c = bc % C;
    const float* upp = up + (size_t)bc * Si * Si;
    const float k1[4] = {1.f, 3.f, 3.f, 1.f};
    float acc = 0.f;
#pragma unroll
    for (int by = 0; by < 4; ++by) {
        int uy = yo - 1 + by;
        if (uy < 0 || uy >= Si) continue;
        float rsum = 0.f;
#pragma unroll
        for (int bx = 0; bx < 4; ++bx) {
            int ux = xo - 1 + bx;
            if (ux < 0 || ux >= Si) continue;
            rsum += k1[bx] * upp[uy * Si + ux];
        }
        acc += k1[by] * rsum;
    }
    float v = acc * (1.f / 16.f) + bias[c];
    v = (v > 0.f ? v : 0.2f * v) * SQRT2;
    out[i] = v;
}

// ---------------- final 1x1 conv 32->3 (+out_bias), no demod/act
__global__ __launch_bounds__(256) void final_kernel(
    const float* __restrict__ x, const float* __restrict__ w,
    const float* __restrict__ style, const float* __restrict__ ob,
    float* __restrict__ out, int HW) {
    int i = blockIdx.x * blockDim.x + threadIdx.x;  // B*HW
    if (i >= 16 * HW) return;
    int b = i / HW, sp = i % HW;
    const float* xp = x + (size_t)b * 32 * HW + sp;
    const float* st = style + b * 32;
    float inv = rsqrtf(32.f);
    float acc0 = 0.f, acc1 = 0.f, acc2 = 0.f;
#pragma unroll
    for (int ci = 0; ci < 32; ++ci) {
        float xv = xp[(size_t)ci * HW] * st[ci];
        acc0 += xv * w[0 * 32 + ci];
        acc1 += xv * w[1 * 32 + ci];
        acc2 += xv * w[2 * 32 + ci];
    }
    out[(size_t)(b * 3 + 0) * HW + sp] = acc0 * inv + ob[0];
    out[(size_t)(b * 3 + 1) * HW + sp] = acc1 * inv + ob[1];
    out[(size_t)(b * 3 + 2) * HW + sp] = acc2 * inv + ob[2];
}

extern "C" void kernel_launch(void* const* d_in, const int* in_sizes, int n_in,
                              void* d_out, int out_size, void* d_ws, size_t ws_size,
                              hipStream_t stream) {
    const float* fg   = (const float*)d_in[0];
    const float* mask = (const float*)d_in[1];
    const float* bg   = (const float*)d_in[2];
    const float* z    = (const float*)d_in[3];
    const float* l0_w = (const float*)d_in[4];
    const float* l0_mw= (const float*)d_in[5];
    const float* l0_mb= (const float*)d_in[6];
    const float* l0_b = (const float*)d_in[7];
    const float* l1_w = (const float*)d_in[8];
    const float* l1_mw= (const float*)d_in[9];
    const float* l1_mb= (const float*)d_in[10];
    const float* l1_b = (const float*)d_in[11];
    const float* l2_w = (const float*)d_in[12];
    const float* l2_mw= (const float*)d_in[13];
    const float* l2_mb= (const float*)d_in[14];
    const float* l2_b = (const float*)d_in[15];
    const float* l3_w = (const float*)d_in[16];
    const float* l3_mw= (const float*)d_in[17];
    const float* l3_mb= (const float*)d_in[18];
    const float* l3_b = (const float*)d_in[19];
    const float* l4_w = (const float*)d_in[20];
    const float* l4_mw= (const float*)d_in[21];
    const float* l4_mb= (const float*)d_in[22];
    const float* l4_b = (const float*)d_in[23];
    const float* fin_w = (const float*)d_in[24];
    const float* fin_mw= (const float*)d_in[25];
    const float* fin_mb= (const float*)d_in[26];
    const float* obias = (const float*)d_in[27];

    float* wsf = (float*)d_ws;
    float* sty0 = wsf + 0;          // 16*256
    float* sty1 = wsf + 4096;       // 16*128
    float* sty2 = wsf + 6144;       // 16*128
    float* sty3 = wsf + 8192;       // 16*64
    float* sty4 = wsf + 9216;       // 16*64
    float* styf = wsf + 10240;      // 16*32
    float* dm0  = wsf + 10752;      // 16*128
    float* dm1  = wsf + 12800;      // 16*128
    float* dm2  = wsf + 14848;      // 16*64
    float* dm3  = wsf + 15872;      // 16*64
    float* dm4  = wsf + 16896;      // 16*32
    float* A    = wsf + 17408;      // 16,777,216 floats
    float* Bb   = A + 16777216;     // 17,040,384 floats

    const float sdScale = 0.04419417382415922f;  // 1/sqrt(512)
    dim3 blk(256);

    // styles
    style_kernel<<<16, blk, 0, stream>>>(z, l0_mw, l0_mb, sty0, 16, 256, sdScale);
    style_kernel<<<8,  blk, 0, stream>>>(z, l1_mw, l1_mb, sty1, 16, 128, sdScale);
    style_kernel<<<8,  blk, 0, stream>>>(z, l2_mw, l2_mb, sty2, 16, 128, sdScale);
    style_kernel<<<4,  blk, 0, stream>>>(z, l3_mw, l3_mb, sty3, 16, 64, sdScale);
    style_kernel<<<4,  blk, 0, stream>>>(z, l4_mw, l4_mb, sty4, 16, 64, sdScale);
    style_kernel<<<2,  blk, 0, stream>>>(z, fin_mw, fin_mb, styf, 16, 32, sdScale);

    // demods
    demod_kernel<<<dim3(128, 16), blk, 0, stream>>>(l0_w, sty0, dm0, 128, 256);
    demod_kernel<<<dim3(128, 16), blk, 0, stream>>>(l1_w, sty1, dm1, 128, 128);
    demod_kernel<<<dim3(64, 16),  blk, 0, stream>>>(l2_w, sty2, dm2, 64, 128);
    demod_kernel<<<dim3(64, 16),  blk, 0, stream>>>(l3_w, sty3, dm3, 64, 64);
    demod_kernel<<<dim3(32, 16),  blk, 0, stream>>>(l4_w, sty4, dm4, 32, 64);

    // composite -> A
    composite_kernel<<<16384, blk, 0, stream>>>(fg, mask, bg, A);

    // l0: conv 256->128 @32, A -> Bb
    conv3x3_kernel<4><<<dim3(1, 32, 16), blk, 0, stream>>>(A, l0_w, sty0, dm0, l0_b, Bb, 256, 128, 32, 1);

    // l1: upconv 128->128, 32 -> 65, Bb -> A (demod applied)
    upconv_kernel<<<dim3(9, 16, 16), blk, 0, stream>>>(Bb, l1_w, sty1, dm1, A, 128, 128, 32, 3);
    // blur+bias+act 65 -> 64, A -> Bb
    blur_bias_act_kernel<<<32768, blk, 0, stream>>>(A, l1_b, Bb, 128, 64, 16 * 128 * 64 * 64);

    // l2: conv 128->64 @64, Bb -> A
    conv3x3_kernel<8><<<dim3(4, 8, 16), blk, 0, stream>>>(Bb, l2_w, sty2, dm2, l2_b, A, 128, 64, 64, 2);

    // l3: upconv 64->64, 64 -> 129, A -> Bb
    upconv_kernel<<<dim3(25, 8, 16), blk, 0, stream>>>(A, l3_w, sty3, dm3, Bb, 64, 64, 64, 5);
    // blur+bias+act 129 -> 128, Bb -> A
    blur_bias_act_kernel<<<65536, blk, 0, stream>>>(Bb, l3_b, A, 64, 128, 16 * 64 * 128 * 128);

    // l4: conv 64->32 @128, A -> Bb
    conv3x3_kernel<8><<<dim3(16, 4, 16), blk, 0, stream>>>(A, l4_w, sty4, dm4, l4_b, Bb, 64, 32, 128, 4);

    // final 1x1 32->3, Bb -> out
    final_kernel<<<1024, blk, 0, stream>>>(Bb, fin_w, styf, obias, (float*)d_out, 16384);
}

// Round 2
// 1165.132 us; speedup vs baseline: 1.7108x; 1.7108x over previous
//
#include <hip/hip_runtime.h>
#include <math.h>

#define SQRT2 1.41421356237309515f

typedef __bf16 bf16x8 __attribute__((ext_vector_type(8)));
typedef float f32x4 __attribute__((ext_vector_type(4)));
typedef unsigned short u16x4 __attribute__((ext_vector_type(4)));
typedef unsigned short u16x8 __attribute__((ext_vector_type(8)));

__device__ __forceinline__ unsigned short f2bf(float f) {
    unsigned u = __builtin_bit_cast(unsigned, f);
    u += 0x7fffu + ((u >> 16) & 1u);
    return (unsigned short)(u >> 16);
}
__device__ __forceinline__ float bf2f(unsigned short s) {
    unsigned u = ((unsigned)s) << 16;
    return __builtin_bit_cast(float, u);
}

// ---------------- style: out[b][ci] = dot(z[b], mw[ci]) * scale + mb[ci]
__global__ __launch_bounds__(256) void style_kernel(
    const float* __restrict__ z, const float* __restrict__ mw,
    const float* __restrict__ mb, float* __restrict__ out,
    int B, int Ci, float scale) {
    int i = blockIdx.x * blockDim.x + threadIdx.x;
    if (i >= B * Ci) return;
    int b = i / Ci, ci = i % Ci;
    const float* zp = z + b * 512;
    const float* wp = mw + ci * 512;
    float acc = 0.f;
#pragma unroll 8
    for (int k = 0; k < 512; ++k) acc += zp[k] * wp[k];
    out[i] = acc * scale + mb[ci];
}

// ---------------- demod: one block per (b, co); reduce sum(w^2 * style^2)
__global__ __launch_bounds__(256) void demod_kernel(
    const float* __restrict__ w, const float* __restrict__ style,
    float* __restrict__ out, int Co, int Ci) {
    int co = blockIdx.x, b = blockIdx.y;
    const float* wp = w + (size_t)co * Ci * 9;
    const float* sp = style + b * Ci;
    float acc = 0.f;
    for (int idx = threadIdx.x; idx < Ci * 9; idx += 256) {
        int ci = idx / 9;
        float v = wp[idx];
        float s = sp[ci];
        acc += v * v * s * s;
    }
    __shared__ float red[4];
    for (int off = 32; off > 0; off >>= 1) acc += __shfl_down(acc, off, 64);
    if ((threadIdx.x & 63) == 0) red[threadIdx.x >> 6] = acc;
    __syncthreads();
    if (threadIdx.x == 0) {
        float t = red[0] + red[1] + red[2] + red[3];
        out[b * Co + co] = rsqrtf(t / (float)(Ci * 9) + 1e-8f);
    }
}

// ---------------- pack weights to bf16, k-order = chunk*288 + t*32 + (ci&31)
__global__ __launch_bounds__(256) void pack_w_kernel(
    const float* __restrict__ w, unsigned short* __restrict__ wp,
    int Co, int Ci, float sInv) {
    int i = blockIdx.x * 256 + threadIdx.x;
    int tot = Co * Ci * 9;
    if (i >= tot) return;
    int K9 = Ci * 9;
    int co = i / K9;
    int r = i - co * K9;
    int ci = r / 9, t = r - ci * 9;
    int dst = co * K9 + (ci >> 5) * 288 + t * 32 + (ci & 31);
    wp[dst] = f2bf(w[i] * sInv);
}

// ---------------- composite: h = fg + (1-mask)*bg -> bf16
__global__ __launch_bounds__(256) void composite_kernel(
    const float* __restrict__ fg, const float* __restrict__ mask,
    const float* __restrict__ bg, unsigned short* __restrict__ out) {
    int i = blockIdx.x * blockDim.x + threadIdx.x;   // 16*256*1024 total
    int sp = i & 1023;
    int b = i >> 18;
    float m = mask[(b << 10) + sp];
    out[i] = f2bf(fg[i] + (1.f - m) * bg[i]);
}

// ---------------- MFMA implicit-GEMM 3x3 conv.
// Input X: bf16 [b][ci][S][S]. Weights W: bf16 packed [co][chunk*288+t*32+cil].
// Block: 16x16 spatial tile, MT*16 output channels, one batch, one K-split.
// Per 32-ci chunk: stage styled input [sp 18x18][cil 32 pad40] + weight slice
// [co][288 pad296] in LDS; 9 taps x (MT x 4) mfma_f32_16x16x32_bf16 per wave.
template <int MT, int SPLITK>
__global__ __launch_bounds__(256, 2) void conv3x3_mfma(
    const unsigned short* __restrict__ X, const unsigned short* __restrict__ W,
    const float* __restrict__ style, const float* __restrict__ demod,
    const float* __restrict__ bias, float* __restrict__ out,
    int Ci, int Co, int S, int TPS, int KCH) {
    __shared__ unsigned short ldsW[MT * 16 * 296];
    __shared__ unsigned short ldsX[324 * 40];
    __shared__ float ldsS[256];
    const int tid = threadIdx.x;
    const int b = blockIdx.z;
    const int gy_ = blockIdx.y;
    const int ks  = (SPLITK > 1) ? (gy_ >> 1) : 0;
    const int cog = (SPLITK > 1) ? (gy_ & 1) : 0;
    const int tile = blockIdx.x;
    const int ty0 = (tile / TPS) * 16, tx0 = (tile % TPS) * 16;
    const int K9 = Ci * 9;
    const int wave = tid >> 6, lane = tid & 63, quad = lane >> 4, l16 = lane & 15;

    for (int i = tid; i < Ci; i += 256) ldsS[i] = style[b * Ci + i];
    __syncthreads();

    f32x4 acc[MT][4];
#pragma unroll
    for (int mt = 0; mt < MT; ++mt)
#pragma unroll
        for (int nt = 0; nt < 4; ++nt) acc[mt][nt] = (f32x4){0.f, 0.f, 0.f, 0.f};

    const unsigned short* wbase = W + (size_t)(cog * MT * 16) * K9;
    const size_t st = (size_t)S * S;

    for (int cc = 0; cc < KCH; ++cc) {
        const int cg = ks * KCH + cc;
        const int ci0 = cg * 32;
        // stage weight slice: MT*16 co x 288 bf16 (16B units)
        for (int u = tid; u < MT * 16 * 36; u += 256) {
            int col = u / 36, o8 = (u - col * 36) * 8;
            u16x8 v = *(const u16x8*)(wbase + (size_t)col * K9 + cg * 288 + o8);
            *(u16x8*)&ldsW[col * 296 + o8] = v;
        }
        // stage styled input: 18x18 halo x 32 ci, bf16, [sp][cil] stride 40
        for (int u = tid; u < 2592; u += 256) {
            int cq = u / 324, sp = u - cq * 324;
            int y = sp / 18, xx = sp - y * 18;
            int gy = ty0 - 1 + y, gx = tx0 - 1 + xx;
            int ci = ci0 + cq * 4;
            u16x4 pk;
            if ((unsigned)gy < (unsigned)S && (unsigned)gx < (unsigned)S) {
                const unsigned short* xp = X + (size_t)(b * Ci + ci) * st + gy * S + gx;
#pragma unroll
                for (int i2 = 0; i2 < 4; ++i2)
                    pk[i2] = f2bf(bf2f(xp[(size_t)i2 * st]) * ldsS[ci + i2]);
            } else {
                pk = (u16x4){0, 0, 0, 0};
            }
            *(u16x4*)&ldsX[sp * 40 + cq * 4] = pk;
        }
        __syncthreads();
#pragma unroll
        for (int t = 0; t < 9; ++t) {
            const int ty = t / 3, tx = t - ty * 3;
            bf16x8 af[MT];
#pragma unroll
            for (int mt = 0; mt < MT; ++mt)
                af[mt] = *(const bf16x8*)(const void*)&ldsW[(mt * 16 + l16) * 296 + t * 32 + quad * 8];
#pragma unroll
            for (int nt = 0; nt < 4; ++nt) {
                int sp = (wave * 4 + nt + ty) * 18 + l16 + tx;
                bf16x8 bf = *(const bf16x8*)(const void*)&ldsX[sp * 40 + quad * 8];
#pragma unroll
                for (int mt = 0; mt < MT; ++mt)
                    acc[mt][nt] = __builtin_amdgcn_mfma_f32_16x16x32_bf16(af[mt], bf, acc[mt][nt], 0, 0, 0);
            }
        }
        __syncthreads();
    }
    // epilogue: D row(co within 16) = quad*4+r, col(pixel x) = l16
    if (SPLITK > 1) {
        const size_t PS = (size_t)16 * Co * S * S;
#pragma unroll
        for (int mt = 0; mt < MT; ++mt)
#pragma unroll
            for (int nt = 0; nt < 4; ++nt) {
                int row = ty0 + wave * 4 + nt, col = tx0 + l16;
#pragma unroll
                for (int r = 0; r < 4; ++r) {
                    int co = cog * (MT * 16) + mt * 16 + quad * 4 + r;
                    out[ks * PS + ((size_t)(b * Co + co) * S + row) * S + col] = acc[mt][nt][r];
                }
            }
    } else {
#pragma unroll
        for (int mt = 0; mt < MT; ++mt)
#pragma unroll
            for (int nt = 0; nt < 4; ++nt) {
                int row = ty0 + wave * 4 + nt, col = tx0 + l16;
#pragma unroll
                for (int r = 0; r < 4; ++r) {
                    int co = mt * 16 + quad * 4 + r;
                    float v = acc[mt][nt][r] * demod[b * Co + co] + bias[co];
                    v = (v > 0.f ? v : 0.2f * v) * SQRT2;
                    out[((size_t)(b * Co + co) * S + row) * S + col] = v;
                }
            }
    }
}

// ---------------- combine split-K partials for l0 + demod + bias + act
__global__ __launch_bounds__(256) void combine_l0_kernel(
    const float* __restrict__ P, const float* __restrict__ demod,
    const float* __restrict__ bias, float* __restrict__ out) {
    int i = blockIdx.x * 256 + threadIdx.x;    // 2,097,152
    int co = (i >> 10) & 127;
    int b = i >> 17;
    float v = P[i] + P[i + (1 << 21)];
    v = v * demod[b * 128 + co] + bias[co];
    v = (v > 0.f ? v : 0.2f * v) * SQRT2;
    out[i] = v;
}

// ---------------- transposed conv (scalar f32, unchanged from round 0)
__global__ __launch_bounds__(256) void upconv_kernel(
    const float* __restrict__ x, const float* __restrict__ w,
    const float* __restrict__ style, const float* __restrict__ demod,
    float* __restrict__ out, int Ci, int Co, int S, int tps) {
    __shared__ float xs[17 * 17];
    int So = 2 * S + 1;
    int tile = blockIdx.x;
    int cog = blockIdx.y, b = blockIdx.z;
    int oy0 = (tile / tps) * 32, ox0 = (tile % tps) * 32;
    int Y0 = oy0 >> 1, X0 = ox0 >> 1;
    int tid = threadIdx.x;
    int qy = tid >> 4, qx = tid & 15;
    float a00[8], a01[8], a10[8], a11[8];
#pragma unroll
    for (int c = 0; c < 8; ++c) { a00[c] = 0.f; a01[c] = 0.f; a10[c] = 0.f; a11[c] = 0.f; }
    float sInv = rsqrtf((float)(Ci * 9));
    const float* wbase = w + (size_t)(cog * 8) * Ci * 9;
    for (int ci = 0; ci < Ci; ++ci) {
        float sc = style[b * Ci + ci] * sInv;
        const float* xp = x + (size_t)(b * Ci + ci) * S * S;
#pragma unroll
        for (int j = 0; j < 2; ++j) {
            int idx = tid + 256 * j;
            if (idx < 17 * 17) {
                int ly = idx / 17, lx = idx % 17;
                int gy = Y0 - 1 + ly, gx = X0 - 1 + lx;
                float v = 0.f;
                if (gy >= 0 && gy < S && gx >= 0 && gx < S) v = xp[gy * S + gx];
                xs[idx] = v * sc;
            }
        }
        __syncthreads();
        float xa = xs[(qy + 1) * 17 + qx + 1];
        float xb = xs[(qy + 1) * 17 + qx];
        float xc = xs[qy * 17 + qx + 1];
        float xd = xs[qy * 17 + qx];
        const float* wp = wbase + ci * 9;
#pragma unroll
        for (int c = 0; c < 8; ++c) {
            const float* wc = wp + (size_t)c * Ci * 9;
            float w00 = wc[0], w01 = wc[1], w02 = wc[2];
            float w10 = wc[3], w11 = wc[4], w12 = wc[5];
            float w20 = wc[6], w21 = wc[7], w22 = wc[8];
            a00[c] += w00 * xa + w02 * xb + w20 * xc + w22 * xd;
            a01[c] += w01 * xa + w21 * xc;
            a10[c] += w10 * xa + w12 * xb;
            a11[c] += w11 * xa;
        }
        __syncthreads();
    }
    int oy = oy0 + 2 * qy, ox = ox0 + 2 * qx;
#pragma unroll
    for (int c = 0; c < 8; ++c) {
        int co = cog * 8 + c;
        float d = demod[b * Co + co];
        float* op = out + (size_t)(b * Co + co) * So * So;
        if (oy < So) {
            if (ox < So) op[oy * So + ox] = a00[c] * d;
            if (ox + 1 < So) op[oy * So + ox + 1] = a01[c] * d;
        }
        if (oy + 1 < So) {
            if (ox < So) op[(oy + 1) * So + ox] = a10[c] * d;
            if (ox + 1 < So) op[(oy + 1) * So + ox + 1] = a11[c] * d;
        }
    }
}

// ---------------- 4x4 blur (pad 1) on (2S+1) -> 2S, bias + lrelu*sqrt2 -> bf16
__global__ __launch_bounds__(256) void blur_bias_act_kernel(
    const float* __restrict__ up, const float* __restrict__ bias,
    unsigned short* __restrict__ out, int C, int S2, int total) {
    int i = blockIdx.x * blockDim.x + threadIdx.x;
    if (i >= total) return;
    int Si = S2 + 1;
    int xo = i % S2;
    int t = i / S2;
    int yo = t % S2;
    int bc = t / S2;
    int c = bc % C;
    const float* upp = up + (size_t)bc * Si * Si;
    const float k1[4] = {1.f, 3.f, 3.f, 1.f};
    float acc = 0.f;
#pragma unroll
    for (int by = 0; by < 4; ++by) {
        int uy = yo - 1 + by;
        if (uy < 0 || uy >= Si) continue;
        float rsum = 0.f;
#pragma unroll
        for (int bx = 0; bx < 4; ++bx) {
            int ux = xo - 1 + bx;
            if (ux < 0 || ux >= Si) continue;
            rsum += k1[bx] * upp[uy * Si + ux];
        }
        acc += k1[by] * rsum;
    }
    float v = acc * (1.f / 16.f) + bias[c];
    v = (v > 0.f ? v : 0.2f * v) * SQRT2;
    out[i] = f2bf(v);
}

// ---------------- final 1x1 conv 32->3 (+out_bias)
__global__ __launch_bounds__(256) void final_kernel(
    const float* __restrict__ x, const float* __restrict__ w,
    const float* __restrict__ style, const float* __restrict__ ob,
    float* __restrict__ out, int HW) {
    int i = blockIdx.x * blockDim.x + threadIdx.x;
    if (i >= 16 * HW) return;
    int b = i / HW, sp = i % HW;
    const float* xp = x + (size_t)b * 32 * HW + sp;
    const float* st = style + b * 32;
    float inv = rsqrtf(32.f);
    float acc0 = 0.f, acc1 = 0.f, acc2 = 0.f;
#pragma unroll
    for (int ci = 0; ci < 32; ++ci) {
        float xv = xp[(size_t)ci * HW] * st[ci];
        acc0 += xv * w[0 * 32 + ci];
        acc1 += xv * w[1 * 32 + ci];
        acc2 += xv * w[2 * 32 + ci];
    }
    out[(size_t)(b * 3 + 0) * HW + sp] = acc0 * inv + ob[0];
    out[(size_t)(b * 3 + 1) * HW + sp] = acc1 * inv + ob[1];
    out[(size_t)(b * 3 + 2) * HW + sp] = acc2 * inv + ob[2];
}

extern "C" void kernel_launch(void* const* d_in, const int* in_sizes, int n_in,
                              void* d_out, int out_size, void* d_ws, size_t ws_size,
                              hipStream_t stream) {
    const float* fg   = (const float*)d_in[0];
    const float* mask = (const float*)d_in[1];
    const float* bg   = (const float*)d_in[2];
    const float* z    = (const float*)d_in[3];
    const float* l0_w = (const float*)d_in[4];
    const float* l0_mw= (const float*)d_in[5];
    const float* l0_mb= (const float*)d_in[6];
    const float* l0_b = (const float*)d_in[7];
    const float* l1_w = (const float*)d_in[8];
    const float* l1_mw= (const float*)d_in[9];
    const float* l1_mb= (const float*)d_in[10];
    const float* l1_b = (const float*)d_in[11];
    const float* l2_w = (const float*)d_in[12];
    const float* l2_mw= (const float*)d_in[13];
    const float* l2_mb= (const float*)d_in[14];
    const float* l2_b = (const float*)d_in[15];
    const float* l3_w = (const float*)d_in[16];
    const float* l3_mw= (const float*)d_in[17];
    const float* l3_mb= (const float*)d_in[18];
    const float* l3_b = (const float*)d_in[19];
    const float* l4_w = (const float*)d_in[20];
    const float* l4_mw= (const float*)d_in[21];
    const float* l4_mb= (const float*)d_in[22];
    const float* l4_b = (const float*)d_in[23];
    const float* fin_w = (const float*)d_in[24];
    const float* fin_mw= (const float*)d_in[25];
    const float* fin_mb= (const float*)d_in[26];
    const float* obias = (const float*)d_in[27];

    float* wsf = (float*)d_ws;
    float* sty0 = wsf + 0;
    float* sty1 = wsf + 4096;
    float* sty2 = wsf + 6144;
    float* sty3 = wsf + 8192;
    float* sty4 = wsf + 9216;
    float* styf = wsf + 10240;
    float* dm0  = wsf + 10752;
    float* dm1  = wsf + 12800;
    float* dm2  = wsf + 14848;
    float* dm3  = wsf + 15872;
    float* dm4  = wsf + 16896;
    unsigned short* wp0 = (unsigned short*)(wsf + 17408);   // 294912 shorts
    unsigned short* wp2 = wp0 + 294912;                     // 73728 shorts
    unsigned short* wp4 = wp2 + 73728;                      // 18432 shorts
    float* A    = wsf + 210944;       // 8,652,800 floats max
    float* Bb   = A + 8652800;        // 17,040,384 floats max
    float* Pbuf = Bb + 2500000;       // 4,194,304 floats (l0 split-K partials)
    unsigned short* Abf  = (unsigned short*)A;
    unsigned short* Bbbf = (unsigned short*)Bb;

    const float sdScale = 0.04419417382415922f;  // 1/sqrt(512)
    dim3 blk(256);

    // styles
    style_kernel<<<16, blk, 0, stream>>>(z, l0_mw, l0_mb, sty0, 16, 256, sdScale);
    style_kernel<<<8,  blk, 0, stream>>>(z, l1_mw, l1_mb, sty1, 16, 128, sdScale);
    style_kernel<<<8,  blk, 0, stream>>>(z, l2_mw, l2_mb, sty2, 16, 128, sdScale);
    style_kernel<<<4,  blk, 0, stream>>>(z, l3_mw, l3_mb, sty3, 16, 64, sdScale);
    style_kernel<<<4,  blk, 0, stream>>>(z, l4_mw, l4_mb, sty4, 16, 64, sdScale);
    style_kernel<<<2,  blk, 0, stream>>>(z, fin_mw, fin_mb, styf, 16, 32, sdScale);

    // demods
    demod_kernel<<<dim3(128, 16), blk, 0, stream>>>(l0_w, sty0, dm0, 128, 256);
    demod_kernel<<<dim3(128, 16), blk, 0, stream>>>(l1_w, sty1, dm1, 128, 128);
    demod_kernel<<<dim3(64, 16),  blk, 0, stream>>>(l2_w, sty2, dm2, 64, 128);
    demod_kernel<<<dim3(64, 16),  blk, 0, stream>>>(l3_w, sty3, dm3, 64, 64);
    demod_kernel<<<dim3(32, 16),  blk, 0, stream>>>(l4_w, sty4, dm4, 32, 64);

    // pack conv weights to bf16 (sInv folded)
    pack_w_kernel<<<(128 * 256 * 9 + 255) / 256, blk, 0, stream>>>(l0_w, wp0, 128, 256, 1.f / 48.f);
    pack_w_kernel<<<(64 * 128 * 9 + 255) / 256,  blk, 0, stream>>>(l2_w, wp2, 64, 128, 0.02946278254943948f);
    pack_w_kernel<<<(32 * 64 * 9 + 255) / 256,   blk, 0, stream>>>(l4_w, wp4, 32, 64, 1.f / 24.f);

    // composite -> A (bf16)
    composite_kernel<<<16384, blk, 0, stream>>>(fg, mask, bg, Abf);

    // l0: MFMA conv 256->128 @32, split-K=2: A(bf16) -> Pbuf, combine -> Bb (f32)
    conv3x3_mfma<4, 2><<<dim3(4, 4, 16), blk, 0, stream>>>(Abf, wp0, sty0, nullptr, nullptr, Pbuf, 256, 128, 32, 2, 4);
    combine_l0_kernel<<<8192, blk, 0, stream>>>(Pbuf, dm0, l0_b, Bb);

    // l1: upconv 128->128, 32 -> 65, Bb(f32) -> A(f32)
    upconv_kernel<<<dim3(9, 16, 16), blk, 0, stream>>>(Bb, l1_w, sty1, dm1, A, 128, 128, 32, 3);
    // blur+bias+act 65 -> 64, A(f32) -> Bb(bf16)
    blur_bias_act_kernel<<<32768, blk, 0, stream>>>(A, l1_b, Bbbf, 128, 64, 16 * 128 * 64 * 64);

    // l2: MFMA conv 128->64 @64, Bb(bf16) -> A(f32)
    conv3x3_mfma<4, 1><<<dim3(16, 1, 16), blk, 0, stream>>>(Bbbf, wp2, sty2, dm2, l2_b, A, 128, 64, 64, 4, 4);

    // l3: upconv 64->64, 64 -> 129, A(f32) -> Bb(f32)
    upconv_kernel<<<dim3(25, 8, 16), blk, 0, stream>>>(A, l3_w, sty3, dm3, Bb, 64, 64, 64, 5);
    // blur+bias+act 129 -> 128, Bb(f32) -> A(bf16)
    blur_bias_act_kernel<<<65536, blk, 0, stream>>>(Bb, l3_b, Abf, 64, 128, 16 * 64 * 128 * 128);

    // l4: MFMA conv 64->32 @128, A(bf16) -> Bb(f32)
    conv3x3_mfma<2, 1><<<dim3(64, 1, 16), blk, 0, stream>>>(Abf, wp4, sty4, dm4, l4_b, Bb, 64, 32, 128, 8, 2);

    // final 1x1 32->3, Bb(f32) -> out
    final_kernel<<<1024, blk, 0, stream>>>(Bb, fin_w, styf, obias, (float*)d_out, 16384);
}

// Round 4
// 944.775 us; speedup vs baseline: 2.1098x; 1.2332x over previous
//
#include <hip/hip_runtime.h>
#include <math.h>

#define SQRT2 1.41421356237309515f

typedef __bf16 bf16x8 __attribute__((ext_vector_type(8)));
typedef float f32x4 __attribute__((ext_vector_type(4)));
typedef unsigned short u16x4 __attribute__((ext_vector_type(4)));
typedef unsigned short u16x8 __attribute__((ext_vector_type(8)));

__device__ __forceinline__ unsigned short f2bf(float f) {
    unsigned u = __builtin_bit_cast(unsigned, f);
    u += 0x7fffu + ((u >> 16) & 1u);
    return (unsigned short)(u >> 16);
}
__device__ __forceinline__ float bf2f(unsigned short s) {
    unsigned u = ((unsigned)s) << 16;
    return __builtin_bit_cast(float, u);
}

// ---------------- style: out[b][ci] = dot(z[b], mw[ci]) * scale + mb[ci]
__global__ __launch_bounds__(256) void style_kernel(
    const float* __restrict__ z, const float* __restrict__ mw,
    const float* __restrict__ mb, float* __restrict__ out,
    int B, int Ci, float scale) {
    int i = blockIdx.x * blockDim.x + threadIdx.x;
    if (i >= B * Ci) return;
    int b = i / Ci, ci = i % Ci;
    const float* zp = z + b * 512;
    const float* wp = mw + ci * 512;
    float acc = 0.f;
#pragma unroll 8
    for (int k = 0; k < 512; ++k) acc += zp[k] * wp[k];
    out[i] = acc * scale + mb[ci];
}

// ---------------- demod: one block per (b, co); reduce sum(w^2 * style^2)
__global__ __launch_bounds__(256) void demod_kernel(
    const float* __restrict__ w, const float* __restrict__ style,
    float* __restrict__ out, int Co, int Ci) {
    int co = blockIdx.x, b = blockIdx.y;
    const float* wp = w + (size_t)co * Ci * 9;
    const float* sp = style + b * Ci;
    float acc = 0.f;
    for (int idx = threadIdx.x; idx < Ci * 9; idx += 256) {
        int ci = idx / 9;
        float v = wp[idx];
        float s = sp[ci];
        acc += v * v * s * s;
    }
    __shared__ float red[4];
    for (int off = 32; off > 0; off >>= 1) acc += __shfl_down(acc, off, 64);
    if ((threadIdx.x & 63) == 0) red[threadIdx.x >> 6] = acc;
    __syncthreads();
    if (threadIdx.x == 0) {
        float t = red[0] + red[1] + red[2] + red[3];
        out[b * Co + co] = rsqrtf(t / (float)(Ci * 9) + 1e-8f);
    }
}

// ---------------- pack weights to bf16, k-order = chunk*288 + t*32 + (ci&31)
__global__ __launch_bounds__(256) void pack_w_kernel(
    const float* __restrict__ w, unsigned short* __restrict__ wp,
    int Co, int Ci, float sInv) {
    int i = blockIdx.x * 256 + threadIdx.x;
    int tot = Co * Ci * 9;
    if (i >= tot) return;
    int K9 = Ci * 9;
    int co = i / K9;
    int r = i - co * K9;
    int ci = r / 9, t = r - ci * 9;
    int dst = co * K9 + (ci >> 5) * 288 + t * 32 + (ci & 31);
    wp[dst] = f2bf(w[i] * sInv);
}

// ---------------- pack upconv weights: parity-tap order
// taps t=0..8: p00:{w0,w2,w6,w8} p01:{w1,w7} p10:{w3,w5} p11:{w4}
__global__ __launch_bounds__(256) void pack_uw_kernel(
    const float* __restrict__ w, unsigned short* __restrict__ wp,
    int Co, int Ci, float sInv) {
    const int t_of[9] = {0, 4, 1, 6, 8, 7, 2, 5, 3};
    int i = blockIdx.x * 256 + threadIdx.x;
    int tot = Co * Ci * 9;
    if (i >= tot) return;
    int K9 = Ci * 9;
    int co = i / K9;
    int r = i - co * K9;
    int ci = r / 9, wi = r - ci * 9;
    int dst = co * K9 + (ci >> 5) * 288 + t_of[wi] * 32 + (ci & 31);
    wp[dst] = f2bf(w[i] * sInv);
}

// ---------------- composite: h = fg + (1-mask)*bg -> bf16
__global__ __launch_bounds__(256) void composite_kernel(
    const float* __restrict__ fg, const float* __restrict__ mask,
    const float* __restrict__ bg, unsigned short* __restrict__ out) {
    int i = blockIdx.x * blockDim.x + threadIdx.x;   // 16*256*1024 total
    int sp = i & 1023;
    int b = i >> 18;
    float m = mask[(b << 10) + sp];
    out[i] = f2bf(fg[i] + (1.f - m) * bg[i]);
}

// ---------------- MFMA implicit-GEMM 3x3 conv.
template <int MT, int SPLITK, int OBF>
__global__ __launch_bounds__(256, 2) void conv3x3_mfma(
    const unsigned short* __restrict__ X, const unsigned short* __restrict__ W,
    const float* __restrict__ style, const float* __restrict__ demod,
    const float* __restrict__ bias, void* __restrict__ outv,
    int Ci, int Co, int S, int TPS, int KCH) {
    __shared__ unsigned short ldsW[MT * 16 * 296];
    __shared__ unsigned short ldsX[324 * 40];
    __shared__ float ldsS[256];
    const int tid = threadIdx.x;
    const int b = blockIdx.z;
    const int gy_ = blockIdx.y;
    const int ks  = (SPLITK > 1) ? (gy_ >> 1) : 0;
    const int cog = (SPLITK > 1) ? (gy_ & 1) : 0;
    const int tile = blockIdx.x;
    const int ty0 = (tile / TPS) * 16, tx0 = (tile % TPS) * 16;
    const int K9 = Ci * 9;
    const int wave = tid >> 6, lane = tid & 63, quad = lane >> 4, l16 = lane & 15;

    for (int i = tid; i < Ci; i += 256) ldsS[i] = style[b * Ci + i];
    __syncthreads();

    f32x4 acc[MT][4];
#pragma unroll
    for (int mt = 0; mt < MT; ++mt)
#pragma unroll
        for (int nt = 0; nt < 4; ++nt) acc[mt][nt] = (f32x4){0.f, 0.f, 0.f, 0.f};

    const unsigned short* wbase = W + (size_t)(cog * MT * 16) * K9;
    const size_t st = (size_t)S * S;

    for (int cc = 0; cc < KCH; ++cc) {
        const int cg = ks * KCH + cc;
        const int ci0 = cg * 32;
        for (int u = tid; u < MT * 16 * 36; u += 256) {
            int col = u / 36, o8 = (u - col * 36) * 8;
            u16x8 v = *(const u16x8*)(wbase + (size_t)col * K9 + cg * 288 + o8);
            *(u16x8*)&ldsW[col * 296 + o8] = v;
        }
        for (int u = tid; u < 2592; u += 256) {
            int cq = u / 324, sp = u - cq * 324;
            int y = sp / 18, xx = sp - y * 18;
            int gy = ty0 - 1 + y, gx = tx0 - 1 + xx;
            int ci = ci0 + cq * 4;
            u16x4 pk;
            if ((unsigned)gy < (unsigned)S && (unsigned)gx < (unsigned)S) {
                const unsigned short* xp = X + (size_t)(b * Ci + ci) * st + gy * S + gx;
#pragma unroll
                for (int i2 = 0; i2 < 4; ++i2)
                    pk[i2] = f2bf(bf2f(xp[(size_t)i2 * st]) * ldsS[ci + i2]);
            } else {
                pk = (u16x4){0, 0, 0, 0};
            }
            *(u16x4*)&ldsX[sp * 40 + cq * 4] = pk;
        }
        __syncthreads();
#pragma unroll
        for (int t = 0; t < 9; ++t) {
            const int ty = t / 3, tx = t - ty * 3;
            bf16x8 af[MT];
#pragma unroll
            for (int mt = 0; mt < MT; ++mt)
                af[mt] = *(const bf16x8*)(const void*)&ldsW[(mt * 16 + l16) * 296 + t * 32 + quad * 8];
#pragma unroll
            for (int nt = 0; nt < 4; ++nt) {
                int sp = (wave * 4 + nt + ty) * 18 + l16 + tx;
                bf16x8 bf = *(const bf16x8*)(const void*)&ldsX[sp * 40 + quad * 8];
#pragma unroll
                for (int mt = 0; mt < MT; ++mt)
                    acc[mt][nt] = __builtin_amdgcn_mfma_f32_16x16x32_bf16(af[mt], bf, acc[mt][nt], 0, 0, 0);
            }
        }
        __syncthreads();
    }
    if (SPLITK > 1) {
        float* out = (float*)outv;
        const size_t PS = (size_t)16 * Co * S * S;
#pragma unroll
        for (int mt = 0; mt < MT; ++mt)
#pragma unroll
            for (int nt = 0; nt < 4; ++nt) {
                int row = ty0 + wave * 4 + nt, col = tx0 + l16;
#pragma unroll
                for (int r = 0; r < 4; ++r) {
                    int co = cog * (MT * 16) + mt * 16 + quad * 4 + r;
                    out[ks * PS + ((size_t)(b * Co + co) * S + row) * S + col] = acc[mt][nt][r];
                }
            }
    } else {
#pragma unroll
        for (int mt = 0; mt < MT; ++mt)
#pragma unroll
            for (int nt = 0; nt < 4; ++nt) {
                int row = ty0 + wave * 4 + nt, col = tx0 + l16;
#pragma unroll
                for (int r = 0; r < 4; ++r) {
                    int co = mt * 16 + quad * 4 + r;
                    float v = acc[mt][nt][r] * demod[b * Co + co] + bias[co];
                    v = (v > 0.f ? v : 0.2f * v) * SQRT2;
                    if (OBF) ((unsigned short*)outv)[((size_t)(b * Co + co) * S + row) * S + col] = f2bf(v);
                    else ((float*)outv)[((size_t)(b * Co + co) * S + row) * S + col] = v;
                }
            }
    }
}

// ---------------- combine split-K partials for l0 + demod + bias + act -> bf16
__global__ __launch_bounds__(256) void combine_l0_kernel(
    const float* __restrict__ P, const float* __restrict__ demod,
    const float* __restrict__ bias, unsigned short* __restrict__ out) {
    int i = blockIdx.x * 256 + threadIdx.x;    // 2,097,152
    int co = (i >> 10) & 127;
    int b = i >> 17;
    float v = P[i] + P[i + (1 << 21)];
    v = v * demod[b * 128 + co] + bias[co];
    v = (v > 0.f ? v : 0.2f * v) * SQRT2;
    out[i] = f2bf(v);
}

// ---------------- MFMA transposed conv (stride 2): quad-parity implicit GEMM.
template <int MT>
__global__ __launch_bounds__(256, 2) void upconv_mfma(
    const unsigned short* __restrict__ X, const unsigned short* __restrict__ W,
    const float* __restrict__ style, const float* __restrict__ demod,
    float* __restrict__ out, int Ci, int Co, int S, int TPS, int KCH) {
    __shared__ unsigned short ldsW[MT * 16 * 296];
    __shared__ unsigned short ldsX[289 * 40];
    __shared__ float ldsS[256];
    const int tid = threadIdx.x;
    const int b = blockIdx.z;
    const int cog = blockIdx.y;
    const int tile = blockIdx.x;
    const int ty0 = (tile / TPS) * 16, tx0 = (tile % TPS) * 16;
    const int K9 = Ci * 9;
    const int So = 2 * S + 1;
    const int wave = tid >> 6, lane = tid & 63, quad = lane >> 4, l16 = lane & 15;

    for (int i = tid; i < Ci; i += 256) ldsS[i] = style[b * Ci + i];
    __syncthreads();

    f32x4 acc[MT][4][4];   // [mt][row nt][parity]
#pragma unroll
    for (int mt = 0; mt < MT; ++mt)
#pragma unroll
        for (int nt = 0; nt < 4; ++nt)
#pragma unroll
            for (int p = 0; p < 4; ++p) acc[mt][nt][p] = (f32x4){0.f, 0.f, 0.f, 0.f};

    const unsigned short* wbase = W + (size_t)(cog * MT * 16) * K9;
    const size_t st = (size_t)S * S;

    for (int cc = 0; cc < KCH; ++cc) {
        const int ci0 = cc * 32;
        for (int u = tid; u < MT * 16 * 36; u += 256) {
            int col = u / 36, o8 = (u - col * 36) * 8;
            u16x8 v = *(const u16x8*)(wbase + (size_t)col * K9 + cc * 288 + o8);
            *(u16x8*)&ldsW[col * 296 + o8] = v;
        }
        // stage styled input 17x17 halo (top/left) x 32 ci
        for (int u = tid; u < 289 * 8; u += 256) {
            int cq = u / 289, sp = u - cq * 289;
            int y = sp / 17, xx = sp - y * 17;
            int gy = ty0 - 1 + y, gx = tx0 - 1 + xx;
            int ci = ci0 + cq * 4;
            u16x4 pk;
            if ((unsigned)gy < (unsigned)S && (unsigned)gx < (unsigned)S) {
                const unsigned short* xp = X + (size_t)(b * Ci + ci) * st + gy * S + gx;
#pragma unroll
                for (int i2 = 0; i2 < 4; ++i2)
                    pk[i2] = f2bf(bf2f(xp[(size_t)i2 * st]) * ldsS[ci + i2]);
            } else {
                pk = (u16x4){0, 0, 0, 0};
            }
            *(u16x4*)&ldsX[sp * 40 + cq * 4] = pk;
        }
        __syncthreads();
        // tap tables: parity, dy, dx (offsets rel. to (Y,X))
        const int TP[9]  = {0, 0, 0, 0, 1, 1, 2, 2, 3};
        const int TDY[9] = {0, 0, -1, -1, 0, -1, 0, 0, 0};
        const int TDX[9] = {0, -1, 0, -1, 0, 0, 0, -1, 0};
#pragma unroll
        for (int t = 0; t < 9; ++t) {
            bf16x8 af[MT];
#pragma unroll
            for (int mt = 0; mt < MT; ++mt)
                af[mt] = *(const bf16x8*)(const void*)&ldsW[(mt * 16 + l16) * 296 + t * 32 + quad * 8];
#pragma unroll
            for (int nt = 0; nt < 4; ++nt) {
                int sp = (wave * 4 + nt + 1 + TDY[t]) * 17 + (l16 + 1 + TDX[t]);
                bf16x8 bfv = *(const bf16x8*)(const void*)&ldsX[sp * 40 + quad * 8];
#pragma unroll
                for (int mt = 0; mt < MT; ++mt)
                    acc[mt][nt][TP[t]] = __builtin_amdgcn_mfma_f32_16x16x32_bf16(af[mt], bfv, acc[mt][nt][TP[t]], 0, 0, 0);
            }
        }
        __syncthreads();
    }
#pragma unroll
    for (int mt = 0; mt < MT; ++mt)
#pragma unroll
        for (int nt = 0; nt < 4; ++nt) {
            int Y = ty0 + wave * 4 + nt, Xc = tx0 + l16;
#pragma unroll
            for (int p = 0; p < 4; ++p) {
                int oy = 2 * Y + (p >> 1), ox = 2 * Xc + (p & 1);
#pragma unroll
                for (int r = 0; r < 4; ++r) {
                    int co = cog * (MT * 16) + mt * 16 + quad * 4 + r;
                    out[((size_t)(b * Co + co) * So + oy) * So + ox] =
                        acc[mt][nt][p][r] * demod[b * Co + co];
                }
            }
        }
}

// ---------------- transposed-conv border: out col 2S (all oy) + row 2S (ox<2S)
__global__ __launch_bounds__(256) void upconv_border_kernel(
    const unsigned short* __restrict__ X, const float* __restrict__ w,
    const float* __restrict__ style, const float* __restrict__ demod,
    float* __restrict__ out, int Ci, int Co, int S, float sInv) {
    int So = 2 * S + 1;
    int P = 2 * So - 1;
    int i = blockIdx.x * 256 + threadIdx.x;
    if (i >= 16 * Co * P) return;
    int pos = i % P;
    int t = i / P;
    int co = t % Co, b = t / Co;
    int oy, ox;
    if (pos < So) { oy = pos; ox = 2 * S; } else { oy = 2 * S; ox = pos - So; }
    int py = oy & 1, px = ox & 1, Y = oy >> 1, Xc = ox >> 1;
    const float* wc = w + (size_t)co * Ci * 9;
    const unsigned short* xb = X + (size_t)b * Ci * S * S;
    const float* sb = style + b * Ci;
    float acc = 0.f;
    for (int ci = 0; ci < Ci; ++ci) {
        float sv = sb[ci];
        const unsigned short* xp = xb + (size_t)ci * S * S;
        const float* wi = wc + ci * 9;
#define LD(yy, xx) ((((unsigned)(yy) < (unsigned)S) && ((unsigned)(xx) < (unsigned)S)) ? bf2f(xp[(yy) * S + (xx)]) * sv : 0.f)
        if (py == 0 && px == 0) acc += wi[0] * LD(Y, Xc) + wi[2] * LD(Y, Xc - 1) + wi[6] * LD(Y - 1, Xc) + wi[8] * LD(Y - 1, Xc - 1);
        else if (py == 0 && px == 1) acc += wi[1] * LD(Y, Xc) + wi[7] * LD(Y - 1, Xc);
        else if (py == 1 && px == 0) acc += wi[3] * LD(Y, Xc) + wi[5] * LD(Y, Xc - 1);
        else acc += wi[4] * LD(Y, Xc);
#undef LD
    }
    out[((size_t)(b * Co + co) * So + oy) * So + ox] = acc * sInv * demod[b * Co + co];
}

// ---------------- 4x4 blur (pad 1) on (2S+1) -> 2S, bias + lrelu*sqrt2 -> bf16
__global__ __launch_bounds__(256) void blur_bias_act_kernel(
    const float* __restrict__ up, const float* __restrict__ bias,
    unsigned short* __restrict__ out, int C, int S2, int total) {
    int i = blockIdx.x * blockDim.x + threadIdx.x;
    if (i >= total) return;
    int Si = S2 + 1;
    int xo = i % S2;
    int t = i / S2;
    int yo = t % S2;
    int bc = t / S2;
    int c = bc % C;
    const float* upp = up + (size_t)bc * Si * Si;
    const float k1[4] = {1.f, 3.f, 3.f, 1.f};
    float acc = 0.f;
#pragma unroll
    for (int by = 0; by < 4; ++by) {
        int uy = yo - 1 + by;
        if (uy < 0 || uy >= Si) continue;
        float rsum = 0.f;
#pragma unroll
        for (int bx = 0; bx < 4; ++bx) {
            int ux = xo - 1 + bx;
            if (ux < 0 || ux >= Si) continue;
            rsum += k1[bx] * upp[uy * Si + ux];
        }
        acc += k1[by] * rsum;
    }
    float v = acc * (1.f / 16.f) + bias[c];
    v = (v > 0.f ? v : 0.2f * v) * SQRT2;
    out[i] = f2bf(v);
}

// ---------------- final 1x1 conv 32->3 (+out_bias)
__global__ __launch_bounds__(256) void final_kernel(
    const float* __restrict__ x, const float* __restrict__ w,
    const float* __restrict__ style, const float* __restrict__ ob,
    float* __restrict__ out, int HW) {
    int i = blockIdx.x * blockDim.x + threadIdx.x;
    if (i >= 16 * HW) return;
    int b = i / HW, sp = i % HW;
    const float* xp = x + (size_t)b * 32 * HW + sp;
    const float* st = style + b * 32;
    float inv = rsqrtf(32.f);
    float acc0 = 0.f, acc1 = 0.f, acc2 = 0.f;
#pragma unroll
    for (int ci = 0; ci < 32; ++ci) {
        float xv = xp[(size_t)ci * HW] * st[ci];
        acc0 += xv * w[0 * 32 + ci];
        acc1 += xv * w[1 * 32 + ci];
        acc2 += xv * w[2 * 32 + ci];
    }
    out[(size_t)(b * 3 + 0) * HW + sp] = acc0 * inv + ob[0];
    out[(size_t)(b * 3 + 1) * HW + sp] = acc1 * inv + ob[1];
    out[(size_t)(b * 3 + 2) * HW + sp] = acc2 * inv + ob[2];
}

extern "C" void kernel_launch(void* const* d_in, const int* in_sizes, int n_in,
                              void* d_out, int out_size, void* d_ws, size_t ws_size,
                              hipStream_t stream) {
    const float* fg   = (const float*)d_in[0];
    const float* mask = (const float*)d_in[1];
    const float* bg   = (const float*)d_in[2];
    const float* z    = (const float*)d_in[3];
    const float* l0_w = (const float*)d_in[4];
    const float* l0_mw= (const float*)d_in[5];
    const float* l0_mb= (const float*)d_in[6];
    const float* l0_b = (const float*)d_in[7];
    const float* l1_w = (const float*)d_in[8];
    const float* l1_mw= (const float*)d_in[9];
    const float* l1_mb= (const float*)d_in[10];
    const float* l1_b = (const float*)d_in[11];
    const float* l2_w = (const float*)d_in[12];
    const float* l2_mw= (const float*)d_in[13];
    const float* l2_mb= (const float*)d_in[14];
    const float* l2_b = (const float*)d_in[15];
    const float* l3_w = (const float*)d_in[16];
    const float* l3_mw= (const float*)d_in[17];
    const float* l3_mb= (const float*)d_in[18];
    const float* l3_b = (const float*)d_in[19];
    const float* l4_w = (const float*)d_in[20];
    const float* l4_mw= (const float*)d_in[21];
    const float* l4_mb= (const float*)d_in[22];
    const float* l4_b = (const float*)d_in[23];
    const float* fin_w = (const float*)d_in[24];
    const float* fin_mw= (const float*)d_in[25];
    const float* fin_mb= (const float*)d_in[26];
    const float* obias = (const float*)d_in[27];

    float* wsf = (float*)d_ws;
    float* sty0 = wsf + 0;
    float* sty1 = wsf + 4096;
    float* sty2 = wsf + 6144;
    float* sty3 = wsf + 8192;
    float* sty4 = wsf + 9216;
    float* styf = wsf + 10240;
    float* dm0  = wsf + 10752;
    float* dm1  = wsf + 12800;
    float* dm2  = wsf + 14848;
    float* dm3  = wsf + 15872;
    float* dm4  = wsf + 16896;
    unsigned short* wp0 = (unsigned short*)(wsf + 17408);   // 294912 sh
    unsigned short* wp2 = wp0 + 294912;                     // 73728 sh
    unsigned short* wp4 = wp2 + 73728;                      // 18432 sh
    unsigned short* uw1 = wp4 + 18432;                      // 147456 sh
    unsigned short* uw3 = uw1 + 147456;                     // 36864 sh
    // ---- activation regions (float offsets). Lifetime-audited, no overlap
    // between any kernel's concurrent read-region and write-region:
    // X0  [303104, 2400256)    composite bf16 (dead after l0 conv)
    // Pbuf[2400256, 6594560)   l0 split-K partials (dead after combine)
    // Y0a [6594560, 7643136)   l0 out bf16 (dead after l1 upconv+border)
    // U1  [7643136, 16295936)  l1 upconv f32 (dead after l1 blur)
    // Y2  = alias X0           l2 out bf16 (dead after l3 upconv+border)
    // U3  [2400256, 19440640)  l3 upconv f32 (ends exactly at Z base)
    // Z   [19440640, 27829248) blur out bf16 (Z1 then Z3)
    // V   = alias U3 head      l4 out f32
    unsigned short* X0  = (unsigned short*)(wsf + 303104);
    float* Pbuf = wsf + 2400256;
    unsigned short* Y0a = (unsigned short*)(wsf + 6594560);
    float* U1   = wsf + 7643136;
    unsigned short* Y2  = X0;
    float* U3   = wsf + 2400256;
    unsigned short* Z   = (unsigned short*)(wsf + 19440640);
    float* V    = wsf + 2400256;

    const float sdScale = 0.04419417382415922f;  // 1/sqrt(512)
    const float sInv1152 = 0.02946278254943948f; // 1/sqrt(1152)
    dim3 blk(256);

    // styles
    style_kernel<<<16, blk, 0, stream>>>(z, l0_mw, l0_mb, sty0, 16, 256, sdScale);
    style_kernel<<<8,  blk, 0, stream>>>(z, l1_mw, l1_mb, sty1, 16, 128, sdScale);
    style_kernel<<<8,  blk, 0, stream>>>(z, l2_mw, l2_mb, sty2, 16, 128, sdScale);
    style_kernel<<<4,  blk, 0, stream>>>(z, l3_mw, l3_mb, sty3, 16, 64, sdScale);
    style_kernel<<<4,  blk, 0, stream>>>(z, l4_mw, l4_mb, sty4, 16, 64, sdScale);
    style_kernel<<<2,  blk, 0, stream>>>(z, fin_mw, fin_mb, styf, 16, 32, sdScale);

    // demods
    demod_kernel<<<dim3(128, 16), blk, 0, stream>>>(l0_w, sty0, dm0, 128, 256);
    demod_kernel<<<dim3(128, 16), blk, 0, stream>>>(l1_w, sty1, dm1, 128, 128);
    demod_kernel<<<dim3(64, 16),  blk, 0, stream>>>(l2_w, sty2, dm2, 64, 128);
    demod_kernel<<<dim3(64, 16),  blk, 0, stream>>>(l3_w, sty3, dm3, 64, 64);
    demod_kernel<<<dim3(32, 16),  blk, 0, stream>>>(l4_w, sty4, dm4, 32, 64);

    // pack weights (sInv folded)
    pack_w_kernel<<<(128 * 256 * 9 + 255) / 256, blk, 0, stream>>>(l0_w, wp0, 128, 256, 1.f / 48.f);
    pack_w_kernel<<<(64 * 128 * 9 + 255) / 256,  blk, 0, stream>>>(l2_w, wp2, 64, 128, sInv1152);
    pack_w_kernel<<<(32 * 64 * 9 + 255) / 256,   blk, 0, stream>>>(l4_w, wp4, 32, 64, 1.f / 24.f);
    pack_uw_kernel<<<(128 * 128 * 9 + 255) / 256, blk, 0, stream>>>(l1_w, uw1, 128, 128, sInv1152);
    pack_uw_kernel<<<(64 * 64 * 9 + 255) / 256,   blk, 0, stream>>>(l3_w, uw3, 64, 64, 1.f / 24.f);

    // composite -> X0 (bf16)
    composite_kernel<<<16384, blk, 0, stream>>>(fg, mask, bg, X0);

    // l0: MFMA conv 256->128 @32, split-K=2 -> Pbuf; combine -> Y0a (bf16)
    conv3x3_mfma<4, 2, 0><<<dim3(4, 4, 16), blk, 0, stream>>>(X0, wp0, sty0, nullptr, nullptr, Pbuf, 256, 128, 32, 2, 4);
    combine_l0_kernel<<<8192, blk, 0, stream>>>(Pbuf, dm0, l0_b, Y0a);

    // l1: MFMA upconv 128->128, 32 -> 65, Y0a -> U1; border fills row/col 2S
    upconv_mfma<2><<<dim3(4, 4, 16), blk, 0, stream>>>(Y0a, uw1, sty1, dm1, U1, 128, 128, 32, 2, 4);
    upconv_border_kernel<<<(16 * 128 * 129 + 255) / 256, blk, 0, stream>>>(Y0a, l1_w, sty1, dm1, U1, 128, 128, 32, sInv1152);
    // blur+bias+act 65 -> 64, U1 -> Z (bf16)
    blur_bias_act_kernel<<<32768, blk, 0, stream>>>(U1, l1_b, Z, 128, 64, 16 * 128 * 64 * 64);

    // l2: MFMA conv 128->64 @64, Z -> Y2 (bf16)
    conv3x3_mfma<4, 1, 1><<<dim3(16, 1, 16), blk, 0, stream>>>(Z, wp2, sty2, dm2, l2_b, Y2, 128, 64, 64, 4, 4);

    // l3: MFMA upconv 64->64, 64 -> 129, Y2 -> U3; border
    upconv_mfma<2><<<dim3(16, 2, 16), blk, 0, stream>>>(Y2, uw3, sty3, dm3, U3, 64, 64, 64, 4, 2);
    upconv_border_kernel<<<(16 * 64 * 257 + 255) / 256, blk, 0, stream>>>(Y2, l3_w, sty3, dm3, U3, 64, 64, 64, 1.f / 24.f);
    // blur+bias+act 129 -> 128, U3 -> Z (bf16)
    blur_bias_act_kernel<<<65536, blk, 0, stream>>>(U3, l3_b, Z, 64, 128, 16 * 64 * 128 * 128);

    // l4: MFMA conv 64->32 @128, Z -> V (f32)
    conv3x3_mfma<2, 1, 0><<<dim3(64, 1, 16), blk, 0, stream>>>(Z, wp4, sty4, dm4, l4_b, V, 64, 32, 128, 8, 2);

    // final 1x1 32->3, V -> out
    final_kernel<<<1024, blk, 0, stream>>>(V, fin_w, styf, obias, (float*)d_out, 16384);
}

// Round 5
// 541.440 us; speedup vs baseline: 3.6815x; 1.7449x over previous
//
#include <hip/hip_runtime.h>
#include <math.h>

#define SQRT2 1.41421356237309515f

typedef __bf16 bf16x8 __attribute__((ext_vector_type(8)));
typedef float f32x4 __attribute__((ext_vector_type(4)));
typedef unsigned short u16x4 __attribute__((ext_vector_type(4)));
typedef unsigned short u16x8 __attribute__((ext_vector_type(8)));

__device__ __forceinline__ unsigned short f2bf(float f) {
    unsigned u = __builtin_bit_cast(unsigned, f);
    u += 0x7fffu + ((u >> 16) & 1u);
    return (unsigned short)(u >> 16);
}
__device__ __forceinline__ float bf2f(unsigned short s) {
    unsigned u = ((unsigned)s) << 16;
    return __builtin_bit_cast(float, u);
}

// ---------------- style: out[b][ci] = dot(z[b], mw[ci]) * scale + mb[ci]
__global__ __launch_bounds__(256) void style_kernel(
    const float* __restrict__ z, const float* __restrict__ mw,
    const float* __restrict__ mb, float* __restrict__ out,
    int B, int Ci, float scale) {
    int i = blockIdx.x * blockDim.x + threadIdx.x;
    if (i >= B * Ci) return;
    int b = i / Ci, ci = i % Ci;
    const float* zp = z + b * 512;
    const float* wp = mw + ci * 512;
    float acc = 0.f;
#pragma unroll 8
    for (int k = 0; k < 512; ++k) acc += zp[k] * wp[k];
    out[i] = acc * scale + mb[ci];
}

// ---------------- demod: one block per (b, co); reduce sum(w^2 * style^2)
__global__ __launch_bounds__(256) void demod_kernel(
    const float* __restrict__ w, const float* __restrict__ style,
    float* __restrict__ out, int Co, int Ci) {
    int co = blockIdx.x, b = blockIdx.y;
    const float* wp = w + (size_t)co * Ci * 9;
    const float* sp = style + b * Ci;
    float acc = 0.f;
    for (int idx = threadIdx.x; idx < Ci * 9; idx += 256) {
        int ci = idx / 9;
        float v = wp[idx];
        float s = sp[ci];
        acc += v * v * s * s;
    }
    __shared__ float red[4];
    for (int off = 32; off > 0; off >>= 1) acc += __shfl_down(acc, off, 64);
    if ((threadIdx.x & 63) == 0) red[threadIdx.x >> 6] = acc;
    __syncthreads();
    if (threadIdx.x == 0) {
        float t = red[0] + red[1] + red[2] + red[3];
        out[b * Co + co] = rsqrtf(t / (float)(Ci * 9) + 1e-8f);
    }
}

// ---------------- pack weights to bf16, k-order = chunk*288 + t*32 + (ci&31)
__global__ __launch_bounds__(256) void pack_w_kernel(
    const float* __restrict__ w, unsigned short* __restrict__ wp,
    int Co, int Ci, float sInv) {
    int i = blockIdx.x * 256 + threadIdx.x;
    int tot = Co * Ci * 9;
    if (i >= tot) return;
    int K9 = Ci * 9;
    int co = i / K9;
    int r = i - co * K9;
    int ci = r / 9, t = r - ci * 9;
    int dst = co * K9 + (ci >> 5) * 288 + t * 32 + (ci & 31);
    wp[dst] = f2bf(w[i] * sInv);
}

// ---------------- pack FUSED upconv+blur weights (36 taps = 4 parity x 3x3)
// E_{py,px}[dd][ee] = (sInv/16) * sum_{r,s} w[r][s]*K[2dd+r-1-py]*K[2ee+s-1-px]
// layout: dst = ((g*KCH + c)*36 + t)*CoG*32 + col*32 + cil
//   co = g*CoG+col, ci = c*32+cil, t = p*9 + dd*3 + ee
__global__ __launch_bounds__(256) void pack_fused_kernel(
    const float* __restrict__ w, unsigned short* __restrict__ ew,
    int Co, int Ci, int CoG, float sInv) {
    int i = blockIdx.x * 256 + threadIdx.x;
    int tot = Co * Ci * 36;
    if (i >= tot) return;
    int cil = i & 31;
    int r1 = i >> 5;
    int col = r1 % CoG; r1 /= CoG;
    int t = r1 % 36; r1 /= 36;
    int KCH = Ci >> 5;
    int c = r1 % KCH;
    int g = r1 / KCH;
    int co = g * CoG + col, ci = c * 32 + cil;
    int p = t / 9, dd = (t % 9) / 3, ee = t % 3;
    int py = p >> 1, px = p & 1;
    const float k1[4] = {1.f, 3.f, 3.f, 1.f};
    const float* wp = w + ((size_t)co * Ci + ci) * 9;
    float acc = 0.f;
#pragma unroll
    for (int r = 0; r < 3; ++r) {
        int ia = 2 * dd + r - 1 - py;
        if (ia < 0 || ia > 3) continue;
#pragma unroll
        for (int s = 0; s < 3; ++s) {
            int ib = 2 * ee + s - 1 - px;
            if (ib < 0 || ib > 3) continue;
            acc += wp[r * 3 + s] * k1[ia] * k1[ib];
        }
    }
    ew[i] = f2bf(acc * sInv * (1.f / 16.f));
}

// ---------------- composite: h = fg + (1-mask)*bg -> bf16
__global__ __launch_bounds__(256) void composite_kernel(
    const float* __restrict__ fg, const float* __restrict__ mask,
    const float* __restrict__ bg, unsigned short* __restrict__ out) {
    int i = blockIdx.x * blockDim.x + threadIdx.x;   // 16*256*1024 total
    int sp = i & 1023;
    int b = i >> 18;
    float m = mask[(b << 10) + sp];
    out[i] = f2bf(fg[i] + (1.f - m) * bg[i]);
}

// ---------------- MFMA implicit-GEMM 3x3 conv.
template <int MT, int SPLITK, int OBF>
__global__ __launch_bounds__(256, 2) void conv3x3_mfma(
    const unsigned short* __restrict__ X, const unsigned short* __restrict__ W,
    const float* __restrict__ style, const float* __restrict__ demod,
    const float* __restrict__ bias, void* __restrict__ outv,
    int Ci, int Co, int S, int TPS, int KCH) {
    __shared__ unsigned short ldsW[MT * 16 * 296];
    __shared__ unsigned short ldsX[324 * 40];
    __shared__ float ldsS[256];
    const int tid = threadIdx.x;
    const int b = blockIdx.z;
    const int gy_ = blockIdx.y;
    const int ks  = (SPLITK > 1) ? (gy_ >> 1) : 0;
    const int cog = (SPLITK > 1) ? (gy_ & 1) : 0;
    const int tile = blockIdx.x;
    const int ty0 = (tile / TPS) * 16, tx0 = (tile % TPS) * 16;
    const int K9 = Ci * 9;
    const int wave = tid >> 6, lane = tid & 63, quad = lane >> 4, l16 = lane & 15;

    for (int i = tid; i < Ci; i += 256) ldsS[i] = style[b * Ci + i];
    __syncthreads();

    f32x4 acc[MT][4];
#pragma unroll
    for (int mt = 0; mt < MT; ++mt)
#pragma unroll
        for (int nt = 0; nt < 4; ++nt) acc[mt][nt] = (f32x4){0.f, 0.f, 0.f, 0.f};

    const unsigned short* wbase = W + (size_t)(cog * MT * 16) * K9;
    const size_t st = (size_t)S * S;

    for (int cc = 0; cc < KCH; ++cc) {
        const int cg = ks * KCH + cc;
        const int ci0 = cg * 32;
        for (int u = tid; u < MT * 16 * 36; u += 256) {
            int col = u / 36, o8 = (u - col * 36) * 8;
            u16x8 v = *(const u16x8*)(wbase + (size_t)col * K9 + cg * 288 + o8);
            *(u16x8*)&ldsW[col * 296 + o8] = v;
        }
        for (int u = tid; u < 2592; u += 256) {
            int cq = u / 324, sp = u - cq * 324;
            int y = sp / 18, xx = sp - y * 18;
            int gy = ty0 - 1 + y, gx = tx0 - 1 + xx;
            int ci = ci0 + cq * 4;
            u16x4 pk;
            if ((unsigned)gy < (unsigned)S && (unsigned)gx < (unsigned)S) {
                const unsigned short* xp = X + (size_t)(b * Ci + ci) * st + gy * S + gx;
#pragma unroll
                for (int i2 = 0; i2 < 4; ++i2)
                    pk[i2] = f2bf(bf2f(xp[(size_t)i2 * st]) * ldsS[ci + i2]);
            } else {
                pk = (u16x4){0, 0, 0, 0};
            }
            *(u16x4*)&ldsX[sp * 40 + cq * 4] = pk;
        }
        __syncthreads();
#pragma unroll
        for (int t = 0; t < 9; ++t) {
            const int ty = t / 3, tx = t - ty * 3;
            bf16x8 af[MT];
#pragma unroll
            for (int mt = 0; mt < MT; ++mt)
                af[mt] = *(const bf16x8*)(const void*)&ldsW[(mt * 16 + l16) * 296 + t * 32 + quad * 8];
#pragma unroll
            for (int nt = 0; nt < 4; ++nt) {
                int sp = (wave * 4 + nt + ty) * 18 + l16 + tx;
                bf16x8 bf = *(const bf16x8*)(const void*)&ldsX[sp * 40 + quad * 8];
#pragma unroll
                for (int mt = 0; mt < MT; ++mt)
                    acc[mt][nt] = __builtin_amdgcn_mfma_f32_16x16x32_bf16(af[mt], bf, acc[mt][nt], 0, 0, 0);
            }
        }
        __syncthreads();
    }
    if (SPLITK > 1) {
        float* out = (float*)outv;
        const size_t PS = (size_t)16 * Co * S * S;
#pragma unroll
        for (int mt = 0; mt < MT; ++mt)
#pragma unroll
            for (int nt = 0; nt < 4; ++nt) {
                int row = ty0 + wave * 4 + nt, col = tx0 + l16;
#pragma unroll
                for (int r = 0; r < 4; ++r) {
                    int co = cog * (MT * 16) + mt * 16 + quad * 4 + r;
                    out[ks * PS + ((size_t)(b * Co + co) * S + row) * S + col] = acc[mt][nt][r];
                }
            }
    } else {
#pragma unroll
        for (int mt = 0; mt < MT; ++mt)
#pragma unroll
            for (int nt = 0; nt < 4; ++nt) {
                int row = ty0 + wave * 4 + nt, col = tx0 + l16;
#pragma unroll
                for (int r = 0; r < 4; ++r) {
                    int co = mt * 16 + quad * 4 + r;
                    float v = acc[mt][nt][r] * demod[b * Co + co] + bias[co];
                    v = (v > 0.f ? v : 0.2f * v) * SQRT2;
                    if (OBF) ((unsigned short*)outv)[((size_t)(b * Co + co) * S + row) * S + col] = f2bf(v);
                    else ((float*)outv)[((size_t)(b * Co + co) * S + row) * S + col] = v;
                }
            }
    }
}

// ---------------- combine split-K partials for l0 + demod + bias + act -> bf16
__global__ __launch_bounds__(256) void combine_l0_kernel(
    const float* __restrict__ P, const float* __restrict__ demod,
    const float* __restrict__ bias, unsigned short* __restrict__ out) {
    int i = blockIdx.x * 256 + threadIdx.x;    // 2,097,152
    int co = (i >> 10) & 127;
    int b = i >> 17;
    float v = P[i] + P[i + (1 << 21)];
    v = v * demod[b * 128 + co] + bias[co];
    v = (v > 0.f ? v : 0.2f * v) * SQRT2;
    out[i] = f2bf(v);
}

// ---------------- FUSED upconv(stride2)+blur MFMA: per output-parity 3x3 conv
// out[2Y+py][2X+px] = sum_{dd,ee} E_p[dd][ee] * x_styled[Y+dd-1][X+ee-1]
// Demod + bias + lrelu*sqrt2 in epilogue, bf16 out, full 2S x 2S (no border).
template <int MT>
__global__ __launch_bounds__(256, 2) void upblur_mfma(
    const unsigned short* __restrict__ X, const unsigned short* __restrict__ EW,
    const float* __restrict__ style, const float* __restrict__ demod,
    const float* __restrict__ bias, unsigned short* __restrict__ out,
    int Ci, int Co, int S, int TPS, int KCH) {
    __shared__ unsigned short ldsX[324 * 40];
    __shared__ float ldsS[256];
    const int CoG = MT * 16;
    const int tid = threadIdx.x;
    const int b = blockIdx.z;
    const int cog = blockIdx.y;
    const int tile = blockIdx.x;
    const int ty0 = (tile / TPS) * 16, tx0 = (tile % TPS) * 16;
    const int wave = tid >> 6, lane = tid & 63, quad = lane >> 4, l16 = lane & 15;

    for (int i = tid; i < Ci; i += 256) ldsS[i] = style[b * Ci + i];
    __syncthreads();

    f32x4 acc[MT][4][4];   // [mt][row nt][parity]
#pragma unroll
    for (int mt = 0; mt < MT; ++mt)
#pragma unroll
        for (int nt = 0; nt < 4; ++nt)
#pragma unroll
            for (int p = 0; p < 4; ++p) acc[mt][nt][p] = (f32x4){0.f, 0.f, 0.f, 0.f};

    const unsigned short* wbase = EW + (size_t)cog * KCH * 36 * CoG * 32;
    const size_t st = (size_t)S * S;

    for (int cc = 0; cc < KCH; ++cc) {
        const int ci0 = cc * 32;
        // stage styled input 18x18 halo x 32 ci
        for (int u = tid; u < 2592; u += 256) {
            int cq = u / 324, sp = u - cq * 324;
            int y = sp / 18, xx = sp - y * 18;
            int gy = ty0 - 1 + y, gx = tx0 - 1 + xx;
            int ci = ci0 + cq * 4;
            u16x4 pk;
            if ((unsigned)gy < (unsigned)S && (unsigned)gx < (unsigned)S) {
                const unsigned short* xp = X + (size_t)(b * Ci + ci) * st + gy * S + gx;
#pragma unroll
                for (int i2 = 0; i2 < 4; ++i2)
                    pk[i2] = f2bf(bf2f(xp[(size_t)i2 * st]) * ldsS[ci + i2]);
            } else {
                pk = (u16x4){0, 0, 0, 0};
            }
            *(u16x4*)&ldsX[sp * 40 + cq * 4] = pk;
        }
        __syncthreads();
        const unsigned short* tb = wbase + (size_t)cc * 36 * CoG * 32;
#pragma unroll
        for (int t = 0; t < 36; ++t) {
            const int p = t / 9, dd = (t % 9) / 3, ee = t % 3;
            bf16x8 af[MT];
#pragma unroll
            for (int mt = 0; mt < MT; ++mt)
                af[mt] = *(const bf16x8*)(const void*)(tb + (size_t)t * CoG * 32 + (mt * 16 + l16) * 32 + quad * 8);
#pragma unroll
            for (int nt = 0; nt < 4; ++nt) {
                int sp = (wave * 4 + nt + dd) * 18 + l16 + ee;
                bf16x8 bfv = *(const bf16x8*)(const void*)&ldsX[sp * 40 + quad * 8];
#pragma unroll
                for (int mt = 0; mt < MT; ++mt)
                    acc[mt][nt][p] = __builtin_amdgcn_mfma_f32_16x16x32_bf16(af[mt], bfv, acc[mt][nt][p], 0, 0, 0);
            }
        }
        __syncthreads();
    }
    const int S2 = 2 * S;
#pragma unroll
    for (int mt = 0; mt < MT; ++mt)
#pragma unroll
        for (int nt = 0; nt < 4; ++nt) {
            int Y = ty0 + wave * 4 + nt, Xc = tx0 + l16;
#pragma unroll
            for (int p = 0; p < 4; ++p) {
                int oy = 2 * Y + (p >> 1), ox = 2 * Xc + (p & 1);
#pragma unroll
                for (int r = 0; r < 4; ++r) {
                    int co = cog * CoG + mt * 16 + quad * 4 + r;
                    float v = acc[mt][nt][p][r] * demod[b * Co + co] + bias[co];
                    v = (v > 0.f ? v : 0.2f * v) * SQRT2;
                    out[((size_t)(b * Co + co) * S2 + oy) * S2 + ox] = f2bf(v);
                }
            }
        }
}

// ---------------- final 1x1 conv 32->3 (+out_bias)
__global__ __launch_bounds__(256) void final_kernel(
    const float* __restrict__ x, const float* __restrict__ w,
    const float* __restrict__ style, const float* __restrict__ ob,
    float* __restrict__ out, int HW) {
    int i = blockIdx.x * blockDim.x + threadIdx.x;
    if (i >= 16 * HW) return;
    int b = i / HW, sp = i % HW;
    const float* xp = x + (size_t)b * 32 * HW + sp;
    const float* st = style + b * 32;
    float inv = rsqrtf(32.f);
    float acc0 = 0.f, acc1 = 0.f, acc2 = 0.f;
#pragma unroll
    for (int ci = 0; ci < 32; ++ci) {
        float xv = xp[(size_t)ci * HW] * st[ci];
        acc0 += xv * w[0 * 32 + ci];
        acc1 += xv * w[1 * 32 + ci];
        acc2 += xv * w[2 * 32 + ci];
    }
    out[(size_t)(b * 3 + 0) * HW + sp] = acc0 * inv + ob[0];
    out[(size_t)(b * 3 + 1) * HW + sp] = acc1 * inv + ob[1];
    out[(size_t)(b * 3 + 2) * HW + sp] = acc2 * inv + ob[2];
}

extern "C" void kernel_launch(void* const* d_in, const int* in_sizes, int n_in,
                              void* d_out, int out_size, void* d_ws, size_t ws_size,
                              hipStream_t stream) {
    const float* fg   = (const float*)d_in[0];
    const float* mask = (const float*)d_in[1];
    const float* bg   = (const float*)d_in[2];
    const float* z    = (const float*)d_in[3];
    const float* l0_w = (const float*)d_in[4];
    const float* l0_mw= (const float*)d_in[5];
    const float* l0_mb= (const float*)d_in[6];
    const float* l0_b = (const float*)d_in[7];
    const float* l1_w = (const float*)d_in[8];
    const float* l1_mw= (const float*)d_in[9];
    const float* l1_mb= (const float*)d_in[10];
    const float* l1_b = (const float*)d_in[11];
    const float* l2_w = (const float*)d_in[12];
    const float* l2_mw= (const float*)d_in[13];
    const float* l2_mb= (const float*)d_in[14];
    const float* l2_b = (const float*)d_in[15];
    const float* l3_w = (const float*)d_in[16];
    const float* l3_mw= (const float*)d_in[17];
    const float* l3_mb= (const float*)d_in[18];
    const float* l3_b = (const float*)d_in[19];
    const float* l4_w = (const float*)d_in[20];
    const float* l4_mw= (const float*)d_in[21];
    const float* l4_mb= (const float*)d_in[22];
    const float* l4_b = (const float*)d_in[23];
    const float* fin_w = (const float*)d_in[24];
    const float* fin_mw= (const float*)d_in[25];
    const float* fin_mb= (const float*)d_in[26];
    const float* obias = (const float*)d_in[27];

    float* wsf = (float*)d_ws;
    float* sty0 = wsf + 0;
    float* sty1 = wsf + 4096;
    float* sty2 = wsf + 6144;
    float* sty3 = wsf + 8192;
    float* sty4 = wsf + 9216;
    float* styf = wsf + 10240;
    float* dm0  = wsf + 10752;
    float* dm1  = wsf + 12800;
    float* dm2  = wsf + 14848;
    float* dm3  = wsf + 15872;
    float* dm4  = wsf + 16896;
    // weights (bf16 shorts), from wsf+17408
    unsigned short* wp0 = (unsigned short*)(wsf + 17408);   // 294912 sh
    unsigned short* wp2 = wp0 + 294912;                     // 73728 sh
    unsigned short* wp4 = wp2 + 73728;                      // 18432 sh
    unsigned short* ew1 = wp4 + 18432;                      // 589824 sh (128*128*36)
    unsigned short* ew3 = ew1 + 589824;                     // 147456 sh (64*64*36)
    // weights end at float offset 17408 + 1124352/2 = 579584
    // ---- activation regions (float offsets), lifetime-audited:
    // X0  [600000, 2697152)    composite bf16; dead after l0 conv
    // Pbuf[2697152, 6891456)   l0 split-K f32; dead after combine
    // Y0a [6891456, 7940032)   l0 out bf16; dead after upblur1
    // Z1  [7940032, 12134336)  l1 fused out bf16; dead after l2 conv
    // Y2  = alias X0           l2 out bf16; dead after upblur3
    // Z3  [12134336, 20522944) l3 fused out bf16; dead after l4 conv
    // V   [2697152, 11085760)  l4 out f32 (over dead Pbuf/Z1); read by final
    unsigned short* X0  = (unsigned short*)(wsf + 600000);
    float* Pbuf = wsf + 2697152;
    unsigned short* Y0a = (unsigned short*)(wsf + 6891456);
    unsigned short* Z1  = (unsigned short*)(wsf + 7940032);
    unsigned short* Y2  = X0;
    unsigned short* Z3  = (unsigned short*)(wsf + 12134336);
    float* V    = wsf + 2697152;

    const float sdScale = 0.04419417382415922f;  // 1/sqrt(512)
    const float sInv1152 = 0.02946278254943948f; // 1/sqrt(1152)
    dim3 blk(256);

    // styles
    style_kernel<<<16, blk, 0, stream>>>(z, l0_mw, l0_mb, sty0, 16, 256, sdScale);
    style_kernel<<<8,  blk, 0, stream>>>(z, l1_mw, l1_mb, sty1, 16, 128, sdScale);
    style_kernel<<<8,  blk, 0, stream>>>(z, l2_mw, l2_mb, sty2, 16, 128, sdScale);
    style_kernel<<<4,  blk, 0, stream>>>(z, l3_mw, l3_mb, sty3, 16, 64, sdScale);
    style_kernel<<<4,  blk, 0, stream>>>(z, l4_mw, l4_mb, sty4, 16, 64, sdScale);
    style_kernel<<<2,  blk, 0, stream>>>(z, fin_mw, fin_mb, styf, 16, 32, sdScale);

    // demods
    demod_kernel<<<dim3(128, 16), blk, 0, stream>>>(l0_w, sty0, dm0, 128, 256);
    demod_kernel<<<dim3(128, 16), blk, 0, stream>>>(l1_w, sty1, dm1, 128, 128);
    demod_kernel<<<dim3(64, 16),  blk, 0, stream>>>(l2_w, sty2, dm2, 64, 128);
    demod_kernel<<<dim3(64, 16),  blk, 0, stream>>>(l3_w, sty3, dm3, 64, 64);
    demod_kernel<<<dim3(32, 16),  blk, 0, stream>>>(l4_w, sty4, dm4, 32, 64);

    // pack weights (sInv folded)
    pack_w_kernel<<<(128 * 256 * 9 + 255) / 256, blk, 0, stream>>>(l0_w, wp0, 128, 256, 1.f / 48.f);
    pack_w_kernel<<<(64 * 128 * 9 + 255) / 256,  blk, 0, stream>>>(l2_w, wp2, 64, 128, sInv1152);
    pack_w_kernel<<<(32 * 64 * 9 + 255) / 256,   blk, 0, stream>>>(l4_w, wp4, 32, 64, 1.f / 24.f);
    pack_fused_kernel<<<(128 * 128 * 36 + 255) / 256, blk, 0, stream>>>(l1_w, ew1, 128, 128, 32, sInv1152);
    pack_fused_kernel<<<(64 * 64 * 36 + 255) / 256,   blk, 0, stream>>>(l3_w, ew3, 64, 64, 32, 1.f / 24.f);

    // composite -> X0 (bf16)
    composite_kernel<<<16384, blk, 0, stream>>>(fg, mask, bg, X0);

    // l0: MFMA conv 256->128 @32, split-K=2 -> Pbuf; combine -> Y0a (bf16)
    conv3x3_mfma<4, 2, 0><<<dim3(4, 4, 16), blk, 0, stream>>>(X0, wp0, sty0, nullptr, nullptr, Pbuf, 256, 128, 32, 2, 4);
    combine_l0_kernel<<<8192, blk, 0, stream>>>(Pbuf, dm0, l0_b, Y0a);

    // l1: FUSED upconv+blur 128->128, 32 -> 64, Y0a -> Z1 (bf16)
    upblur_mfma<2><<<dim3(4, 4, 16), blk, 0, stream>>>(Y0a, ew1, sty1, dm1, l1_b, Z1, 128, 128, 32, 2, 4);

    // l2: MFMA conv 128->64 @64, Z1 -> Y2 (bf16)
    conv3x3_mfma<4, 1, 1><<<dim3(16, 1, 16), blk, 0, stream>>>(Z1, wp2, sty2, dm2, l2_b, Y2, 128, 64, 64, 4, 4);

    // l3: FUSED upconv+blur 64->64, 64 -> 128, Y2 -> Z3 (bf16)
    upblur_mfma<2><<<dim3(16, 2, 16), blk, 0, stream>>>(Y2, ew3, sty3, dm3, l3_b, Z3, 64, 64, 64, 4, 2);

    // l4: MFMA conv 64->32 @128, Z3 -> V (f32)
    conv3x3_mfma<2, 1, 0><<<dim3(64, 1, 16), blk, 0, stream>>>(Z3, wp4, sty4, dm4, l4_b, V, 64, 32, 128, 8, 2);

    // final 1x1 32->3, V -> out
    final_kernel<<<1024, blk, 0, stream>>>(V, fin_w, styf, obias, (float*)d_out, 16384);
}

// Round 6
// 431.159 us; speedup vs baseline: 4.6232x; 1.2558x over previous
//
#include <hip/hip_runtime.h>
#include <math.h>

#define SQRT2 1.41421356237309515f

typedef __bf16 bf16x8 __attribute__((ext_vector_type(8)));
typedef float f32x4 __attribute__((ext_vector_type(4)));
typedef unsigned short u16x4 __attribute__((ext_vector_type(4)));
typedef unsigned short u16x8 __attribute__((ext_vector_type(8)));

__device__ __forceinline__ unsigned short f2bf(float f) {
    unsigned u = __builtin_bit_cast(unsigned, f);
    u += 0x7fffu + ((u >> 16) & 1u);
    return (unsigned short)(u >> 16);
}

// ---------------- style: out[b][ci] = (dot(z,mw)*scale + mb) * outmul
__global__ __launch_bounds__(256) void style_kernel(
    const float* __restrict__ z, const float* __restrict__ mw,
    const float* __restrict__ mb, float* __restrict__ out,
    int B, int Ci, float scale, float outmul) {
    int i = blockIdx.x * blockDim.x + threadIdx.x;
    if (i >= B * Ci) return;
    int b = i / Ci, ci = i % Ci;
    const float* zp = z + b * 512;
    const float* wp = mw + ci * 512;
    float acc = 0.f;
#pragma unroll 8
    for (int k = 0; k < 512; ++k) acc += zp[k] * wp[k];
    out[i] = (acc * scale + mb[ci]) * outmul;
}

// ---------------- demod: one block per (b, co); reduce sum(w^2 * style^2)
__global__ __launch_bounds__(256) void demod_kernel(
    const float* __restrict__ w, const float* __restrict__ style,
    float* __restrict__ out, int Co, int Ci) {
    int co = blockIdx.x, b = blockIdx.y;
    const float* wp = w + (size_t)co * Ci * 9;
    const float* sp = style + b * Ci;
    float acc = 0.f;
    for (int idx = threadIdx.x; idx < Ci * 9; idx += 256) {
        int ci = idx / 9;
        float v = wp[idx];
        float s = sp[ci];
        acc += v * v * s * s;
    }
    __shared__ float red[4];
    for (int off = 32; off > 0; off >>= 1) acc += __shfl_down(acc, off, 64);
    if ((threadIdx.x & 63) == 0) red[threadIdx.x >> 6] = acc;
    __syncthreads();
    if (threadIdx.x == 0) {
        float t = red[0] + red[1] + red[2] + red[3];
        out[b * Co + co] = rsqrtf(t / (float)(Ci * 9) + 1e-8f);
    }
}

// ---------------- pack conv weights for direct-global fragment loads:
// dst = ((g*KT + c)*9 + t)*16*32 + col*32 + cil ; co = g*16+col, ci = c*32+cil
__global__ __launch_bounds__(256) void pack_cw_kernel(
    const float* __restrict__ w, unsigned short* __restrict__ wp,
    int Co, int Ci, float sInv) {
    int i = blockIdx.x * 256 + threadIdx.x;
    if (i >= Co * Ci * 9) return;
    int cil = i & 31;
    int r1 = i >> 5;
    int col = r1 & 15; r1 >>= 4;
    int t = r1 % 9; r1 /= 9;
    int KT = Ci >> 5;
    int c = r1 % KT, g = r1 / KT;
    int co = g * 16 + col, ci = c * 32 + cil;
    wp[i] = f2bf(w[((size_t)co * Ci + ci) * 9 + t] * sInv);
}

// ---------------- pack FUSED upconv+blur weights (36 taps = 4 parity x 3x3)
// E_{py,px}[dd][ee] = (sInv/16) * sum_{r,s} w[r][s]*K[2dd+r-1-py]*K[2ee+s-1-px]
// dst = ((g*KT + c)*36 + p*9+dd*3+ee)*32*32 + col*32 + cil (CoG=32)
__global__ __launch_bounds__(256) void pack_fused_kernel(
    const float* __restrict__ w, unsigned short* __restrict__ ew,
    int Co, int Ci, float sInv) {
    int i = blockIdx.x * 256 + threadIdx.x;
    if (i >= Co * Ci * 36) return;
    int cil = i & 31;
    int r1 = i >> 5;
    int col = r1 % 32; r1 /= 32;
    int t = r1 % 36; r1 /= 36;
    int KT = Ci >> 5;
    int c = r1 % KT, g = r1 / KT;
    int co = g * 32 + col, ci = c * 32 + cil;
    int p = t / 9, dd = (t % 9) / 3, ee = t % 3;
    int py = p >> 1, px = p & 1;
    const float k1[4] = {1.f, 3.f, 3.f, 1.f};
    const float* wq = w + ((size_t)co * Ci + ci) * 9;
    float acc = 0.f;
#pragma unroll
    for (int r = 0; r < 3; ++r) {
        int ia = 2 * dd + r - 1 - py;
        if (ia < 0 || ia > 3) continue;
#pragma unroll
        for (int s = 0; s < 3; ++s) {
            int ib = 2 * ee + s - 1 - px;
            if (ib < 0 || ib > 3) continue;
            acc += wq[r * 3 + s] * k1[ia] * k1[ib];
        }
    }
    ew[i] = f2bf(acc * sInv * (1.f / 16.f));
}

// ---------------- composite + transpose to channel-last, x sty0 -> bf16
// block = (b, y); out[b][y][x][ci]
__global__ __launch_bounds__(256) void composite_cl_kernel(
    const float* __restrict__ fg, const float* __restrict__ mask,
    const float* __restrict__ bg, const float* __restrict__ sty0,
    unsigned short* __restrict__ out) {
    __shared__ unsigned short ldsT[32 * 264];
    int blk = blockIdx.x;
    int b = blk >> 5, y = blk & 31;
    int t = threadIdx.x;
    int x = t & 31, cr = t >> 5;
    const float* sb = sty0 + b * 256;
    float m = 1.f - mask[(b << 10) + (y << 5) + x];
    for (int k = 0; k < 32; ++k) {
        int ci = k * 8 + cr;
        size_t idx = ((size_t)(b * 256 + ci) << 10) + (y << 5) + x;
        float v = fg[idx] + m * bg[idx];
        ldsT[x * 264 + ci] = f2bf(v * sb[ci]);
    }
    __syncthreads();
    int xx = t >> 5, cu = t & 31;
#pragma unroll
    for (int ph = 0; ph < 4; ++ph) {
        int px = ph * 8 + xx;
        u16x8 v = *(const u16x8*)&ldsT[px * 264 + cu * 8];
        *(u16x8*)(out + (((size_t)(b * 32 + y) * 32 + px) << 8) + cu * 8) = v;
    }
}

// ---------------- MFMA 3x3 conv, channel-last pre-styled input, MT=1 (16 co).
// OUTMODE 0: f32 split-K partial [ks][b][y][x][Co]
// OUTMODE 1: bf16 epilogue (demod+bias+lrelu*sqrt2*nextsty) channel-last
// OUTMODE 2: f32  epilogue (same) channel-last
template <int OUTMODE>
__global__ __launch_bounds__(256, 4) void conv3x3_cl(
    const unsigned short* __restrict__ X, const unsigned short* __restrict__ W,
    const float* __restrict__ demod, const float* __restrict__ bias,
    const float* __restrict__ nextsty, void* __restrict__ outv,
    int Ci, int Co, int S, int TPS, int KCH, int cogN) {
    __shared__ unsigned short ldsX[324 * 40];
    const int tid = threadIdx.x;
    const int b = blockIdx.z;
    const int gy_ = blockIdx.y;
    const int ks = gy_ / cogN, cog = gy_ % cogN;
    const int tile = blockIdx.x;
    const int ty0 = (tile / TPS) * 16, tx0 = (tile % TPS) * 16;
    const int KT = Ci >> 5;
    const int wave = tid >> 6, lane = tid & 63, quad = lane >> 4, l16 = lane & 15;

    f32x4 acc[4];
#pragma unroll
    for (int nt = 0; nt < 4; ++nt) acc[nt] = (f32x4){0.f, 0.f, 0.f, 0.f};

    for (int cc = 0; cc < KCH; ++cc) {
        const int cg = ks * KCH + cc;
        const int ci0 = cg * 32;
        for (int u = tid; u < 1296; u += 256) {
            int sp = u >> 2, cq = u & 3;
            int y = sp / 18, xx = sp - y * 18;
            int gy = ty0 - 1 + y, gx = tx0 - 1 + xx;
            u16x8 pk = (u16x8){0, 0, 0, 0, 0, 0, 0, 0};
            if ((unsigned)gy < (unsigned)S && (unsigned)gx < (unsigned)S)
                pk = *(const u16x8*)(X + ((size_t)(b * S + gy) * S + gx) * Ci + ci0 + cq * 8);
            *(u16x8*)&ldsX[sp * 40 + cq * 8] = pk;
        }
        __syncthreads();
        const unsigned short* wt = W + (((size_t)cog * KT + cg) * 9) * 512;
#pragma unroll
        for (int t = 0; t < 9; ++t) {
            const int ty = t / 3, tx = t - ty * 3;
            bf16x8 af = *(const bf16x8*)(const void*)(wt + t * 512 + l16 * 32 + quad * 8);
#pragma unroll
            for (int nt = 0; nt < 4; ++nt) {
                int sp = (wave * 4 + nt + ty) * 18 + l16 + tx;
                bf16x8 bv = *(const bf16x8*)(const void*)&ldsX[sp * 40 + quad * 8];
                acc[nt] = __builtin_amdgcn_mfma_f32_16x16x32_bf16(af, bv, acc[nt], 0, 0, 0);
            }
        }
        __syncthreads();
    }
    const int co0 = cog * 16 + quad * 4;
    const int col = tx0 + l16;
    if (OUTMODE == 0) {
        float* out = (float*)outv;
        const size_t PS = (size_t)16 * S * S * Co;
#pragma unroll
        for (int nt = 0; nt < 4; ++nt) {
            int row = ty0 + wave * 4 + nt;
            *(f32x4*)&out[ks * PS + ((size_t)(b * S + row) * S + col) * Co + co0] = acc[nt];
        }
    } else {
        f32x4 dm = *(const f32x4*)&demod[b * Co + co0];
        f32x4 bi = *(const f32x4*)&bias[co0];
        f32x4 ns = *(const f32x4*)&nextsty[b * Co + co0];
#pragma unroll
        for (int nt = 0; nt < 4; ++nt) {
            int row = ty0 + wave * 4 + nt;
            size_t base = ((size_t)(b * S + row) * S + col) * Co + co0;
            if (OUTMODE == 1) {
                u16x4 st;
#pragma unroll
                for (int r = 0; r < 4; ++r) {
                    float v = acc[nt][r] * dm[r] + bi[r];
                    v = (v > 0.f ? v : 0.2f * v) * SQRT2 * ns[r];
                    st[r] = f2bf(v);
                }
                *(u16x4*)((unsigned short*)outv + base) = st;
            } else {
                f32x4 st;
#pragma unroll
                for (int r = 0; r < 4; ++r) {
                    float v = acc[nt][r] * dm[r] + bi[r];
                    st[r] = (v > 0.f ? v : 0.2f * v) * SQRT2 * ns[r];
                }
                *(f32x4*)((float*)outv + base) = st;
            }
        }
    }
}

// ---------------- combine split-K partials for l0 (+demod+bias+act+sty1) -> bf16
__global__ __launch_bounds__(256) void combine_l0_kernel(
    const float* __restrict__ P, const float* __restrict__ demod,
    const float* __restrict__ bias, const float* __restrict__ sty1,
    unsigned short* __restrict__ out) {
    int i = blockIdx.x * 256 + threadIdx.x;    // [b][y][x][128]
    int co = i & 127;
    int b = i >> 17;
    float v = P[i] + P[i + (1 << 21)];
    v = v * demod[b * 128 + co] + bias[co];
    v = (v > 0.f ? v : 0.2f * v) * SQRT2 * sty1[b * 128 + co];
    out[i] = f2bf(v);
}

// ---------------- FUSED upconv+blur MFMA, channel-last, parity-per-block, MT=2.
// blockIdx.y = cog*4 + parity. out[2Y+py][2X+px][co] bf16 x nextsty.
__global__ __launch_bounds__(256, 3) void upblur_cl(
    const unsigned short* __restrict__ X, const unsigned short* __restrict__ EW,
    const float* __restrict__ demod, const float* __restrict__ bias,
    const float* __restrict__ nextsty, unsigned short* __restrict__ out,
    int Ci, int Co, int S, int TPS) {
    __shared__ unsigned short ldsX[324 * 40];
    const int tid = threadIdx.x;
    const int b = blockIdx.z;
    const int cog = blockIdx.y >> 2, p = blockIdx.y & 3;
    const int tile = blockIdx.x;
    const int ty0 = (tile / TPS) * 16, tx0 = (tile % TPS) * 16;
    const int KT = Ci >> 5;
    const int wave = tid >> 6, lane = tid & 63, quad = lane >> 4, l16 = lane & 15;

    f32x4 acc[2][4];
#pragma unroll
    for (int mt = 0; mt < 2; ++mt)
#pragma unroll
        for (int nt = 0; nt < 4; ++nt) acc[mt][nt] = (f32x4){0.f, 0.f, 0.f, 0.f};

    for (int cc = 0; cc < KT; ++cc) {
        const int ci0 = cc * 32;
        for (int u = tid; u < 1296; u += 256) {
            int sp = u >> 2, cq = u & 3;
            int y = sp / 18, xx = sp - y * 18;
            int gy = ty0 - 1 + y, gx = tx0 - 1 + xx;
            u16x8 pk = (u16x8){0, 0, 0, 0, 0, 0, 0, 0};
            if ((unsigned)gy < (unsigned)S && (unsigned)gx < (unsigned)S)
                pk = *(const u16x8*)(X + ((size_t)(b * S + gy) * S + gx) * Ci + ci0 + cq * 8);
            *(u16x8*)&ldsX[sp * 40 + cq * 8] = pk;
        }
        __syncthreads();
        const unsigned short* wt = EW + (((size_t)cog * KT + cc) * 36 + p * 9) * 1024;
#pragma unroll
        for (int t = 0; t < 9; ++t) {
            const int dd = t / 3, ee = t - dd * 3;
            bf16x8 af[2];
#pragma unroll
            for (int mt = 0; mt < 2; ++mt)
                af[mt] = *(const bf16x8*)(const void*)(wt + t * 1024 + (mt * 16 + l16) * 32 + quad * 8);
#pragma unroll
            for (int nt = 0; nt < 4; ++nt) {
                int sp = (wave * 4 + nt + dd) * 18 + l16 + ee;
                bf16x8 bv = *(const bf16x8*)(const void*)&ldsX[sp * 40 + quad * 8];
#pragma unroll
                for (int mt = 0; mt < 2; ++mt)
                    acc[mt][nt] = __builtin_amdgcn_mfma_f32_16x16x32_bf16(af[mt], bv, acc[mt][nt], 0, 0, 0);
            }
        }
        __syncthreads();
    }
    const int S2 = 2 * S;
    const int py = p >> 1, px = p & 1;
    const int Xc = tx0 + l16, ox = 2 * Xc + px;
#pragma unroll
    for (int mt = 0; mt < 2; ++mt) {
        const int co0 = cog * 32 + mt * 16 + quad * 4;
        f32x4 dm = *(const f32x4*)&demod[b * Co + co0];
        f32x4 bi = *(const f32x4*)&bias[co0];
        f32x4 ns = *(const f32x4*)&nextsty[b * Co + co0];
#pragma unroll
        for (int nt = 0; nt < 4; ++nt) {
            int Y = ty0 + wave * 4 + nt, oy = 2 * Y + py;
            u16x4 st;
#pragma unroll
            for (int r = 0; r < 4; ++r) {
                float v = acc[mt][nt][r] * dm[r] + bi[r];
                v = (v > 0.f ? v : 0.2f * v) * SQRT2 * ns[r];
                st[r] = f2bf(v);
            }
            *(u16x4*)(out + ((size_t)(b * S2 + oy) * S2 + ox) * Co + co0) = st;
        }
    }
}

// ---------------- final 1x1 conv 32->3 (+out_bias); V channel-last f32,
// styf*rsqrt(32) already folded into V by l4 epilogue.
__global__ __launch_bounds__(256) void final_cl_kernel(
    const float* __restrict__ V, const float* __restrict__ w,
    const float* __restrict__ ob, float* __restrict__ out) {
    int i = blockIdx.x * 256 + threadIdx.x;   // 16*16384 pixels
    int b = i >> 14, sp = i & 16383;
    const float* vp = V + (size_t)i * 32;
    float a0 = 0.f, a1 = 0.f, a2 = 0.f;
#pragma unroll
    for (int ci = 0; ci < 32; ++ci) {
        float xv = vp[ci];
        a0 += xv * w[ci];
        a1 += xv * w[32 + ci];
        a2 += xv * w[64 + ci];
    }
    out[((size_t)b * 3 + 0) * 16384 + sp] = a0 + ob[0];
    out[((size_t)b * 3 + 1) * 16384 + sp] = a1 + ob[1];
    out[((size_t)b * 3 + 2) * 16384 + sp] = a2 + ob[2];
}

extern "C" void kernel_launch(void* const* d_in, const int* in_sizes, int n_in,
                              void* d_out, int out_size, void* d_ws, size_t ws_size,
                              hipStream_t stream) {
    const float* fg   = (const float*)d_in[0];
    const float* mask = (const float*)d_in[1];
    const float* bg   = (const float*)d_in[2];
    const float* z    = (const float*)d_in[3];
    const float* l0_w = (const float*)d_in[4];
    const float* l0_mw= (const float*)d_in[5];
    const float* l0_mb= (const float*)d_in[6];
    const float* l0_b = (const float*)d_in[7];
    const float* l1_w = (const float*)d_in[8];
    const float* l1_mw= (const float*)d_in[9];
    const float* l1_mb= (const float*)d_in[10];
    const float* l1_b = (const float*)d_in[11];
    const float* l2_w = (const float*)d_in[12];
    const float* l2_mw= (const float*)d_in[13];
    const float* l2_mb= (const float*)d_in[14];
    const float* l2_b = (const float*)d_in[15];
    const float* l3_w = (const float*)d_in[16];
    const float* l3_mw= (const float*)d_in[17];
    const float* l3_mb= (const float*)d_in[18];
    const float* l3_b = (const float*)d_in[19];
    const float* l4_w = (const float*)d_in[20];
    const float* l4_mw= (const float*)d_in[21];
    const float* l4_mb= (const float*)d_in[22];
    const float* l4_b = (const float*)d_in[23];
    const float* fin_w = (const float*)d_in[24];
    const float* fin_mw= (const float*)d_in[25];
    const float* fin_mb= (const float*)d_in[26];
    const float* obias = (const float*)d_in[27];

    float* wsf = (float*)d_ws;
    float* sty0 = wsf + 0;
    float* sty1 = wsf + 4096;
    float* sty2 = wsf + 6144;
    float* sty3 = wsf + 8192;
    float* sty4 = wsf + 9216;
    float* styf = wsf + 10240;   // pre-scaled by 1/sqrt(32)
    float* dm0  = wsf + 10752;
    float* dm1  = wsf + 12800;
    float* dm2  = wsf + 14848;
    float* dm3  = wsf + 15872;
    float* dm4  = wsf + 16896;
    unsigned short* wp0 = (unsigned short*)(wsf + 17408);   // 294912 sh
    unsigned short* wp2 = wp0 + 294912;                     // 73728 sh
    unsigned short* wp4 = wp2 + 73728;                      // 18432 sh
    unsigned short* ew1 = wp4 + 18432;                      // 589824 sh
    unsigned short* ew3 = ew1 + 589824;                     // 147456 sh
    // ---- channel-last activations (float offsets), lifetime-audited:
    // X0 [600000, 2697152)    composite bf16 [b][32][32][256]; dead after l0
    // Pb [2697152, 6891456)   l0 split-K f32 [2][b][32][32][128]; dead after combine
    // Y0 [6891456, 7940032)   l0 out bf16 [b][32][32][128]; dead after upblur1
    // Z1 [7940032, 12134336)  l1 out bf16 [b][64][64][128]; dead after l2
    // Y2 = alias X0           l2 out bf16 [b][64][64][64]; dead after upblur3
    // Z3 [12134336, 20522944) l3 out bf16 [b][128][128][64]; dead after l4
    // V  [2697152, 11085760)  l4 out f32 [b][128][128][32] (over dead Pb/Y0/Z1)
    unsigned short* X0  = (unsigned short*)(wsf + 600000);
    float* Pbuf = wsf + 2697152;
    unsigned short* Y0  = (unsigned short*)(wsf + 6891456);
    unsigned short* Z1  = (unsigned short*)(wsf + 7940032);
    unsigned short* Y2  = X0;
    unsigned short* Z3  = (unsigned short*)(wsf + 12134336);
    float* V    = wsf + 2697152;

    const float sdScale = 0.04419417382415922f;  // 1/sqrt(512)
    const float sInv1152 = 0.02946278254943948f; // 1/sqrt(1152)
    dim3 blk(256);

    // styles (styf pre-scaled by 1/sqrt(32))
    style_kernel<<<16, blk, 0, stream>>>(z, l0_mw, l0_mb, sty0, 16, 256, sdScale, 1.f);
    style_kernel<<<8,  blk, 0, stream>>>(z, l1_mw, l1_mb, sty1, 16, 128, sdScale, 1.f);
    style_kernel<<<8,  blk, 0, stream>>>(z, l2_mw, l2_mb, sty2, 16, 128, sdScale, 1.f);
    style_kernel<<<4,  blk, 0, stream>>>(z, l3_mw, l3_mb, sty3, 16, 64, sdScale, 1.f);
    style_kernel<<<4,  blk, 0, stream>>>(z, l4_mw, l4_mb, sty4, 16, 64, sdScale, 1.f);
    style_kernel<<<2,  blk, 0, stream>>>(z, fin_mw, fin_mb, styf, 16, 32, sdScale, 0.1767766952966369f);

    // demods (need RAW styles: styf not used for demod)
    demod_kernel<<<dim3(128, 16), blk, 0, stream>>>(l0_w, sty0, dm0, 128, 256);
    demod_kernel<<<dim3(128, 16), blk, 0, stream>>>(l1_w, sty1, dm1, 128, 128);
    demod_kernel<<<dim3(64, 16),  blk, 0, stream>>>(l2_w, sty2, dm2, 64, 128);
    demod_kernel<<<dim3(64, 16),  blk, 0, stream>>>(l3_w, sty3, dm3, 64, 64);
    demod_kernel<<<dim3(32, 16),  blk, 0, stream>>>(l4_w, sty4, dm4, 32, 64);

    // pack weights (sInv folded)
    pack_cw_kernel<<<(128 * 256 * 9 + 255) / 256, blk, 0, stream>>>(l0_w, wp0, 128, 256, 1.f / 48.f);
    pack_cw_kernel<<<(64 * 128 * 9 + 255) / 256,  blk, 0, stream>>>(l2_w, wp2, 64, 128, sInv1152);
    pack_cw_kernel<<<(32 * 64 * 9 + 255) / 256,   blk, 0, stream>>>(l4_w, wp4, 32, 64, 1.f / 24.f);
    pack_fused_kernel<<<(128 * 128 * 36 + 255) / 256, blk, 0, stream>>>(l1_w, ew1, 128, 128, sInv1152);
    pack_fused_kernel<<<(64 * 64 * 36 + 255) / 256,   blk, 0, stream>>>(l3_w, ew3, 64, 64, 1.f / 24.f);

    // composite (NCHW -> channel-last, x sty0) -> X0
    composite_cl_kernel<<<512, blk, 0, stream>>>(fg, mask, bg, sty0, X0);

    // l0: conv 256->128 @32, MT=1, split-K=2 -> Pbuf; combine (x sty1) -> Y0
    conv3x3_cl<0><<<dim3(4, 16, 16), blk, 0, stream>>>(X0, wp0, nullptr, nullptr, nullptr, Pbuf, 256, 128, 32, 2, 4, 8);
    combine_l0_kernel<<<8192, blk, 0, stream>>>(Pbuf, dm0, l0_b, sty1, Y0);

    // l1: fused upconv+blur 128->128, 32->64, parity-split (x sty2) -> Z1
    upblur_cl<<<dim3(4, 16, 16), blk, 0, stream>>>(Y0, ew1, dm1, l1_b, sty2, Z1, 128, 128, 32, 2);

    // l2: conv 128->64 @64 (x sty3) -> Y2
    conv3x3_cl<1><<<dim3(16, 4, 16), blk, 0, stream>>>(Z1, wp2, dm2, l2_b, sty3, Y2, 128, 64, 64, 4, 4, 4);

    // l3: fused upconv+blur 64->64, 64->128, parity-split (x sty4) -> Z3
    upblur_cl<<<dim3(16, 8, 16), blk, 0, stream>>>(Y2, ew3, dm3, l3_b, sty4, Z3, 64, 64, 64, 4);

    // l4: conv 64->32 @128 (x styf/sqrt32) -> V (f32)
    conv3x3_cl<2><<<dim3(64, 2, 16), blk, 0, stream>>>(Z3, wp4, dm4, l4_b, styf, V, 64, 32, 128, 8, 2, 2);

    // final 1x1 32->3 -> out
    final_cl_kernel<<<1024, blk, 0, stream>>>(V, fin_w, obias, (float*)d_out);
}

// Round 7
// 303.769 us; speedup vs baseline: 6.5620x; 1.4194x over previous
//
#include <hip/hip_runtime.h>
#include <math.h>

#define SQRT2 1.41421356237309515f

typedef __bf16 bf16x8 __attribute__((ext_vector_type(8)));
typedef float f32x4 __attribute__((ext_vector_type(4)));
typedef unsigned short u16x4 __attribute__((ext_vector_type(4)));
typedef unsigned short u16x8 __attribute__((ext_vector_type(8)));

__device__ __forceinline__ unsigned short f2bf(float f) {
    unsigned u = __builtin_bit_cast(unsigned, f);
    u += 0x7fffu + ((u >> 16) & 1u);
    return (unsigned short)(u >> 16);
}

// ---------------- all styles in one kernel (shapes hardcoded)
__global__ __launch_bounds__(256) void style_all(
    const float* __restrict__ z,
    const float* __restrict__ mw0, const float* __restrict__ mb0,
    const float* __restrict__ mw1, const float* __restrict__ mb1,
    const float* __restrict__ mw2, const float* __restrict__ mb2,
    const float* __restrict__ mw3, const float* __restrict__ mb3,
    const float* __restrict__ mw4, const float* __restrict__ mb4,
    const float* __restrict__ mwf, const float* __restrict__ mbf,
    float* __restrict__ s0, float* __restrict__ s1, float* __restrict__ s2,
    float* __restrict__ s3, float* __restrict__ s4, float* __restrict__ sf) {
    int i = blockIdx.x * 256 + threadIdx.x;
    const float* mw; const float* mb; float* o; int Ci, idx; float mul = 1.f;
    if (i < 4096)       { mw = mw0; mb = mb0; o = s0; Ci = 256; idx = i; }
    else if (i < 6144)  { mw = mw1; mb = mb1; o = s1; Ci = 128; idx = i - 4096; }
    else if (i < 8192)  { mw = mw2; mb = mb2; o = s2; Ci = 128; idx = i - 6144; }
    else if (i < 9216)  { mw = mw3; mb = mb3; o = s3; Ci = 64;  idx = i - 8192; }
    else if (i < 10240) { mw = mw4; mb = mb4; o = s4; Ci = 64;  idx = i - 9216; }
    else if (i < 10752) { mw = mwf; mb = mbf; o = sf; Ci = 32;  idx = i - 10240;
                          mul = 0.1767766952966369f; }  // 1/sqrt(32)
    else return;
    int b = idx / Ci, ci = idx % Ci;
    const float* zp = z + b * 512;
    const float* wp = mw + ci * 512;
    float acc = 0.f;
#pragma unroll 8
    for (int k = 0; k < 512; ++k) acc += zp[k] * wp[k];
    o[idx] = (acc * 0.04419417382415922f + mb[ci]) * mul;
}

// ---------------- all demods: one wave per (b,co), layer decoded by wave id
__global__ __launch_bounds__(256) void demod_all(
    const float* __restrict__ w0, const float* __restrict__ w1,
    const float* __restrict__ w2, const float* __restrict__ w3,
    const float* __restrict__ w4,
    const float* __restrict__ s0, const float* __restrict__ s1,
    const float* __restrict__ s2, const float* __restrict__ s3,
    const float* __restrict__ s4,
    float* __restrict__ d0, float* __restrict__ d1, float* __restrict__ d2,
    float* __restrict__ d3, float* __restrict__ d4) {
    int wid = blockIdx.x * 4 + (threadIdx.x >> 6);
    int lane = threadIdx.x & 63;
    const float* w; const float* s; float* d; int Co, Ci, idx;
    if (wid < 2048)      { w = w0; s = s0; d = d0; Co = 128; Ci = 256; idx = wid; }
    else if (wid < 4096) { w = w1; s = s1; d = d1; Co = 128; Ci = 128; idx = wid - 2048; }
    else if (wid < 5120) { w = w2; s = s2; d = d2; Co = 64;  Ci = 128; idx = wid - 4096; }
    else if (wid < 6144) { w = w3; s = s3; d = d3; Co = 64;  Ci = 64;  idx = wid - 5120; }
    else if (wid < 6656) { w = w4; s = s4; d = d4; Co = 32;  Ci = 64;  idx = wid - 6144; }
    else return;
    int b = idx / Co, co = idx % Co;
    const float* wp = w + (size_t)co * Ci * 9;
    const float* sp = s + b * Ci;
    float acc = 0.f;
    for (int k = lane; k < Ci * 9; k += 64) {
        int ci = k / 9;
        float v = wp[k], sv = sp[ci];
        acc += v * v * sv * sv;
    }
    for (int off = 32; off > 0; off >>= 1) acc += __shfl_down(acc, off);
    if (lane == 0) d[b * Co + co] = rsqrtf(acc / (float)(Ci * 9) + 1e-8f);
}

// ---------------- pack helpers (CoG = 32 for all)
__device__ __forceinline__ void pack_cw_elem(
    const float* __restrict__ w, unsigned short* __restrict__ dst,
    int i, int Ci, int KT, float sInv) {
    int cil = i & 31;
    int r = i >> 5;
    int col = r % 32; r /= 32;
    int t = r % 9; r /= 9;
    int c = r % KT, g = r / KT;
    int co = g * 32 + col, ci = c * 32 + cil;
    dst[i] = f2bf(w[((size_t)co * Ci + ci) * 9 + t] * sInv);
}
__device__ __forceinline__ void pack_fused_elem(
    const float* __restrict__ w, unsigned short* __restrict__ dst,
    int i, int Ci, int KT, float sInv) {
    int cil = i & 31;
    int r = i >> 5;
    int col = r % 32; r /= 32;
    int t = r % 36; r /= 36;
    int c = r % KT, g = r / KT;
    int co = g * 32 + col, ci = c * 32 + cil;
    int p = t / 9, dd = (t % 9) / 3, ee = t % 3;
    int py = p >> 1, px = p & 1;
    const float k1[4] = {1.f, 3.f, 3.f, 1.f};
    const float* wq = w + ((size_t)co * Ci + ci) * 9;
    float acc = 0.f;
#pragma unroll
    for (int rr = 0; rr < 3; ++rr) {
        int ia = 2 * dd + rr - 1 - py;
        if (ia < 0 || ia > 3) continue;
#pragma unroll
        for (int ss = 0; ss < 3; ++ss) {
            int ib = 2 * ee + ss - 1 - px;
            if (ib < 0 || ib > 3) continue;
            acc += wq[rr * 3 + ss] * k1[ia] * k1[ib];
        }
    }
    dst[i] = f2bf(acc * sInv * (1.f / 16.f));
}

// ---------------- all weight packs in one kernel (segment ranges hardcoded)
__global__ __launch_bounds__(256) void pack_all(
    const float* __restrict__ l0w, const float* __restrict__ l1w,
    const float* __restrict__ l2w, const float* __restrict__ l3w,
    const float* __restrict__ l4w, unsigned short* __restrict__ base) {
    const float sInv1152 = 0.02946278254943948f;
    int i = blockIdx.x * 256 + threadIdx.x;
    if (i < 294912)       pack_cw_elem(l0w, base, i, 256, 8, 1.f / 48.f);
    else if (i < 368640)  pack_cw_elem(l2w, base + 294912, i - 294912, 128, 4, sInv1152);
    else if (i < 387072)  pack_cw_elem(l4w, base + 368640, i - 368640, 64, 2, 1.f / 24.f);
    else if (i < 976896)  pack_fused_elem(l1w, base + 387072, i - 387072, 128, 4, sInv1152);
    else if (i < 1124352) pack_fused_elem(l3w, base + 976896, i - 976896, 64, 2, 1.f / 24.f);
}

// ---------------- composite + transpose to channel-last, x sty0 -> bf16
__global__ __launch_bounds__(256) void composite_cl_kernel(
    const float* __restrict__ fg, const float* __restrict__ mask,
    const float* __restrict__ bg, const float* __restrict__ sty0,
    unsigned short* __restrict__ out) {
    __shared__ unsigned short ldsT[32 * 264];
    int blk = blockIdx.x;
    int b = blk >> 5, y = blk & 31;
    int t = threadIdx.x;
    int x = t & 31, cr = t >> 5;
    const float* sb = sty0 + b * 256;
    float m = 1.f - mask[(b << 10) + (y << 5) + x];
    for (int k = 0; k < 32; ++k) {
        int ci = k * 8 + cr;
        size_t idx = ((size_t)(b * 256 + ci) << 10) + (y << 5) + x;
        float v = fg[idx] + m * bg[idx];
        ldsT[x * 264 + ci] = f2bf(v * sb[ci]);
    }
    __syncthreads();
    int xx = t >> 5, cu = t & 31;
#pragma unroll
    for (int ph = 0; ph < 4; ++ph) {
        int px = ph * 8 + xx;
        u16x8 v = *(const u16x8*)&ldsT[px * 264 + cu * 8];
        *(u16x8*)(out + (((size_t)(b * 32 + y) * 32 + px) << 8) + cu * 8) = v;
    }
}

// ---------------- MFMA 3x3 conv, channel-last pre-styled input, MT=2 (32 co).
// OUTMODE 0: f32 split-K partial; OUTMODE 1: bf16 epilogue channel-last;
// OUTMODE 3: l4 + fused final 1x1 (32->3) -> d_out NCHW f32.
template <int OUTMODE>
__global__ __launch_bounds__(256, 4) void conv3x3_cl(
    const unsigned short* __restrict__ X, const unsigned short* __restrict__ W,
    const float* __restrict__ demod, const float* __restrict__ bias,
    const float* __restrict__ nextsty, const float* __restrict__ finw,
    const float* __restrict__ ob, void* __restrict__ outv,
    int Ci, int Co, int S, int TPS, int KCH, int cogN) {
    __shared__ unsigned short ldsX[324 * 40];
    const int tid = threadIdx.x;
    const int b = blockIdx.z;
    const int gy_ = blockIdx.y;
    const int ks = gy_ / cogN, cog = gy_ % cogN;
    const int tile = blockIdx.x;
    const int ty0 = (tile / TPS) * 16, tx0 = (tile % TPS) * 16;
    const int KT = Ci >> 5;
    const int wave = tid >> 6, lane = tid & 63, quad = lane >> 4, l16 = lane & 15;

    f32x4 acc[2][4];
#pragma unroll
    for (int mt = 0; mt < 2; ++mt)
#pragma unroll
        for (int nt = 0; nt < 4; ++nt) acc[mt][nt] = (f32x4){0.f, 0.f, 0.f, 0.f};

    for (int cc = 0; cc < KCH; ++cc) {
        const int cg = ks * KCH + cc;
        const int ci0 = cg * 32;
        for (int u = tid; u < 1296; u += 256) {
            int sp = u >> 2, cq = u & 3;
            int y = sp / 18, xx = sp - y * 18;
            int gy = ty0 - 1 + y, gx = tx0 - 1 + xx;
            u16x8 pk = (u16x8){0, 0, 0, 0, 0, 0, 0, 0};
            if ((unsigned)gy < (unsigned)S && (unsigned)gx < (unsigned)S)
                pk = *(const u16x8*)(X + ((size_t)(b * S + gy) * S + gx) * Ci + ci0 + cq * 8);
            *(u16x8*)&ldsX[sp * 40 + cq * 8] = pk;
        }
        __syncthreads();
        const unsigned short* wt = W + (((size_t)cog * KT + cg) * 9) * 1024;
#pragma unroll
        for (int t = 0; t < 9; ++t) {
            const int ty = t / 3, tx = t - ty * 3;
            bf16x8 af[2];
#pragma unroll
            for (int mt = 0; mt < 2; ++mt)
                af[mt] = *(const bf16x8*)(const void*)(wt + t * 1024 + (mt * 16 + l16) * 32 + quad * 8);
#pragma unroll
            for (int nt = 0; nt < 4; ++nt) {
                int sp = (wave * 4 + nt + ty) * 18 + l16 + tx;
                bf16x8 bv = *(const bf16x8*)(const void*)&ldsX[sp * 40 + quad * 8];
#pragma unroll
                for (int mt = 0; mt < 2; ++mt)
                    acc[mt][nt] = __builtin_amdgcn_mfma_f32_16x16x32_bf16(af[mt], bv, acc[mt][nt], 0, 0, 0);
            }
        }
        __syncthreads();
    }
    const int col = tx0 + l16;
    if (OUTMODE == 0) {
        float* out = (float*)outv;
        const size_t PS = (size_t)16 * S * S * Co;
#pragma unroll
        for (int mt = 0; mt < 2; ++mt) {
            int co0 = cog * 32 + mt * 16 + quad * 4;
#pragma unroll
            for (int nt = 0; nt < 4; ++nt) {
                int row = ty0 + wave * 4 + nt;
                *(f32x4*)&out[ks * PS + ((size_t)(b * S + row) * S + col) * Co + co0] = acc[mt][nt];
            }
        }
    } else if (OUTMODE == 1) {
#pragma unroll
        for (int mt = 0; mt < 2; ++mt) {
            int co0 = cog * 32 + mt * 16 + quad * 4;
            f32x4 dm = *(const f32x4*)&demod[b * Co + co0];
            f32x4 bi = *(const f32x4*)&bias[co0];
            f32x4 ns = *(const f32x4*)&nextsty[b * Co + co0];
#pragma unroll
            for (int nt = 0; nt < 4; ++nt) {
                int row = ty0 + wave * 4 + nt;
                size_t base = ((size_t)(b * S + row) * S + col) * Co + co0;
                u16x4 st;
#pragma unroll
                for (int r = 0; r < 4; ++r) {
                    float v = acc[mt][nt][r] * dm[r] + bi[r];
                    v = (v > 0.f ? v : 0.2f * v) * SQRT2 * ns[r];
                    st[r] = f2bf(v);
                }
                *(u16x4*)((unsigned short*)outv + base) = st;
            }
        }
    } else {
        // l4 epilogue + fused final 1x1 (Co=32, cog=0): each l16 column's 4
        // quads x 2 mt hold all 32 channels of pixel (row,col).
        f32x4 dm[2], bi[2], ns[2];
        float fw[3][2][4];
#pragma unroll
        for (int mt = 0; mt < 2; ++mt) {
            int c0 = mt * 16 + quad * 4;
            dm[mt] = *(const f32x4*)&demod[b * Co + c0];
            bi[mt] = *(const f32x4*)&bias[c0];
            ns[mt] = *(const f32x4*)&nextsty[b * Co + c0];
#pragma unroll
            for (int c = 0; c < 3; ++c)
#pragma unroll
                for (int r = 0; r < 4; ++r) fw[c][mt][r] = finw[c * 32 + c0 + r];
        }
        float* out = (float*)outv;
        float ob0 = ob[0], ob1 = ob[1], ob2 = ob[2];
#pragma unroll
        for (int nt = 0; nt < 4; ++nt) {
            int row = ty0 + wave * 4 + nt;
            float p0 = 0.f, p1 = 0.f, p2 = 0.f;
#pragma unroll
            for (int mt = 0; mt < 2; ++mt)
#pragma unroll
                for (int r = 0; r < 4; ++r) {
                    float v = acc[mt][nt][r] * dm[mt][r] + bi[mt][r];
                    v = (v > 0.f ? v : 0.2f * v) * SQRT2 * ns[mt][r];
                    p0 += v * fw[0][mt][r];
                    p1 += v * fw[1][mt][r];
                    p2 += v * fw[2][mt][r];
                }
            p0 += __shfl_xor(p0, 16); p0 += __shfl_xor(p0, 32);
            p1 += __shfl_xor(p1, 16); p1 += __shfl_xor(p1, 32);
            p2 += __shfl_xor(p2, 16); p2 += __shfl_xor(p2, 32);
            if (quad == 0) {
                size_t base = (((size_t)b * 3) << 14) + (row << 7) + col;
                out[base] = p0 + ob0;
                out[base + 16384] = p1 + ob1;
                out[base + 32768] = p2 + ob2;
            }
        }
    }
}

// ---------------- combine split-K partials for l0 (+demod+bias+act+sty1) -> bf16
__global__ __launch_bounds__(256) void combine_l0_kernel(
    const float* __restrict__ P, const float* __restrict__ demod,
    const float* __restrict__ bias, const float* __restrict__ sty1,
    unsigned short* __restrict__ out) {
    int i = blockIdx.x * 256 + threadIdx.x;    // [b][y][x][128]
    int co = i & 127;
    int b = i >> 17;
    float v = P[i] + P[i + (1 << 21)];
    v = v * demod[b * 128 + co] + bias[co];
    v = (v > 0.f ? v : 0.2f * v) * SQRT2 * sty1[b * 128 + co];
    out[i] = f2bf(v);
}

// ---------------- FUSED upconv+blur MFMA, channel-last, parity-per-block, MT=2.
__global__ __launch_bounds__(256, 4) void upblur_cl(
    const unsigned short* __restrict__ X, const unsigned short* __restrict__ EW,
    const float* __restrict__ demod, const float* __restrict__ bias,
    const float* __restrict__ nextsty, unsigned short* __restrict__ out,
    int Ci, int Co, int S, int TPS) {
    __shared__ unsigned short ldsX[324 * 40];
    const int tid = threadIdx.x;
    const int b = blockIdx.z;
    const int cog = blockIdx.y >> 2, p = blockIdx.y & 3;
    const int tile = blockIdx.x;
    const int ty0 = (tile / TPS) * 16, tx0 = (tile % TPS) * 16;
    const int KT = Ci >> 5;
    const int wave = tid >> 6, lane = tid & 63, quad = lane >> 4, l16 = lane & 15;

    f32x4 acc[2][4];
#pragma unroll
    for (int mt = 0; mt < 2; ++mt)
#pragma unroll
        for (int nt = 0; nt < 4; ++nt) acc[mt][nt] = (f32x4){0.f, 0.f, 0.f, 0.f};

    for (int cc = 0; cc < KT; ++cc) {
        const int ci0 = cc * 32;
        for (int u = tid; u < 1296; u += 256) {
            int sp = u >> 2, cq = u & 3;
            int y = sp / 18, xx = sp - y * 18;
            int gy = ty0 - 1 + y, gx = tx0 - 1 + xx;
            u16x8 pk = (u16x8){0, 0, 0, 0, 0, 0, 0, 0};
            if ((unsigned)gy < (unsigned)S && (unsigned)gx < (unsigned)S)
                pk = *(const u16x8*)(X + ((size_t)(b * S + gy) * S + gx) * Ci + ci0 + cq * 8);
            *(u16x8*)&ldsX[sp * 40 + cq * 8] = pk;
        }
        __syncthreads();
        const unsigned short* wt = EW + (((size_t)cog * KT + cc) * 36 + p * 9) * 1024;
#pragma unroll
        for (int t = 0; t < 9; ++t) {
            const int dd = t / 3, ee = t - dd * 3;
            bf16x8 af[2];
#pragma unroll
            for (int mt = 0; mt < 2; ++mt)
                af[mt] = *(const bf16x8*)(const void*)(wt + t * 1024 + (mt * 16 + l16) * 32 + quad * 8);
#pragma unroll
            for (int nt = 0; nt < 4; ++nt) {
                int sp = (wave * 4 + nt + dd) * 18 + l16 + ee;
                bf16x8 bv = *(const bf16x8*)(const void*)&ldsX[sp * 40 + quad * 8];
#pragma unroll
                for (int mt = 0; mt < 2; ++mt)
                    acc[mt][nt] = __builtin_amdgcn_mfma_f32_16x16x32_bf16(af[mt], bv, acc[mt][nt], 0, 0, 0);
            }
        }
        __syncthreads();
    }
    const int S2 = 2 * S;
    const int py = p >> 1, px = p & 1;
    const int Xc = tx0 + l16, ox = 2 * Xc + px;
#pragma unroll
    for (int mt = 0; mt < 2; ++mt) {
        const int co0 = cog * 32 + mt * 16 + quad * 4;
        f32x4 dm = *(const f32x4*)&demod[b * Co + co0];
        f32x4 bi = *(const f32x4*)&bias[co0];
        f32x4 ns = *(const f32x4*)&nextsty[b * Co + co0];
#pragma unroll
        for (int nt = 0; nt < 4; ++nt) {
            int Y = ty0 + wave * 4 + nt, oy = 2 * Y + py;
            u16x4 st;
#pragma unroll
            for (int r = 0; r < 4; ++r) {
                float v = acc[mt][nt][r] * dm[r] + bi[r];
                v = (v > 0.f ? v : 0.2f * v) * SQRT2 * ns[r];
                st[r] = f2bf(v);
            }
            *(u16x4*)(out + ((size_t)(b * S2 + oy) * S2 + ox) * Co + co0) = st;
        }
    }
}

extern "C" void kernel_launch(void* const* d_in, const int* in_sizes, int n_in,
                              void* d_out, int out_size, void* d_ws, size_t ws_size,
                              hipStream_t stream) {
    const float* fg   = (const float*)d_in[0];
    const float* mask = (const float*)d_in[1];
    const float* bg   = (const float*)d_in[2];
    const float* z    = (const float*)d_in[3];
    const float* l0_w = (const float*)d_in[4];
    const float* l0_mw= (const float*)d_in[5];
    const float* l0_mb= (const float*)d_in[6];
    const float* l0_b = (const float*)d_in[7];
    const float* l1_w = (const float*)d_in[8];
    const float* l1_mw= (const float*)d_in[9];
    const float* l1_mb= (const float*)d_in[10];
    const float* l1_b = (const float*)d_in[11];
    const float* l2_w = (const float*)d_in[12];
    const float* l2_mw= (const float*)d_in[13];
    const float* l2_mb= (const float*)d_in[14];
    const float* l2_b = (const float*)d_in[15];
    const float* l3_w = (const float*)d_in[16];
    const float* l3_mw= (const float*)d_in[17];
    const float* l3_mb= (const float*)d_in[18];
    const float* l3_b = (const float*)d_in[19];
    const float* l4_w = (const float*)d_in[20];
    const float* l4_mw= (const float*)d_in[21];
    const float* l4_mb= (const float*)d_in[22];
    const float* l4_b = (const float*)d_in[23];
    const float* fin_w = (const float*)d_in[24];
    const float* fin_mw= (const float*)d_in[25];
    const float* fin_mb= (const float*)d_in[26];
    const float* obias = (const float*)d_in[27];

    float* wsf = (float*)d_ws;
    float* sty0 = wsf + 0;
    float* sty1 = wsf + 4096;
    float* sty2 = wsf + 6144;
    float* sty3 = wsf + 8192;
    float* sty4 = wsf + 9216;
    float* styf = wsf + 10240;   // pre-scaled by 1/sqrt(32)
    float* dm0  = wsf + 10752;
    float* dm1  = wsf + 12800;
    float* dm2  = wsf + 14848;
    float* dm3  = wsf + 15872;
    float* dm4  = wsf + 16896;
    // packed weights: one region, segment offsets match pack_all
    unsigned short* wbase = (unsigned short*)(wsf + 17408);
    unsigned short* wp0 = wbase;            // 294912 sh
    unsigned short* wp2 = wbase + 294912;   // 73728 sh
    unsigned short* wp4 = wbase + 368640;   // 18432 sh
    unsigned short* ew1 = wbase + 387072;   // 589824 sh
    unsigned short* ew3 = wbase + 976896;   // 147456 sh, end 1124352 sh
    // ---- channel-last activations (float offsets), lifetime-audited:
    // X0 [600000, 2697152)    composite bf16 [b][32][32][256]; dead after l0
    // Pb [2697152, 6891456)   l0 split-K f32 [2][b][32][32][128]; dead after combine
    // Y0 [6891456, 7940032)   l0 out bf16 [b][32][32][128]; dead after upblur1
    // Z1 [7940032, 12134336)  l1 out bf16 [b][64][64][128]; dead after l2
    // Y2 = alias X0           l2 out bf16 [b][64][64][64]; dead after upblur3
    // Z3 [12134336, 20522944) l3 out bf16 [b][128][128][64]; dead after l4
    unsigned short* X0  = (unsigned short*)(wsf + 600000);
    float* Pbuf = wsf + 2697152;
    unsigned short* Y0  = (unsigned short*)(wsf + 6891456);
    unsigned short* Z1  = (unsigned short*)(wsf + 7940032);
    unsigned short* Y2  = X0;
    unsigned short* Z3  = (unsigned short*)(wsf + 12134336);

    dim3 blk(256);

    // prep: 3 fused kernels
    style_all<<<42, blk, 0, stream>>>(z, l0_mw, l0_mb, l1_mw, l1_mb, l2_mw, l2_mb,
                                      l3_mw, l3_mb, l4_mw, l4_mb, fin_mw, fin_mb,
                                      sty0, sty1, sty2, sty3, sty4, styf);
    demod_all<<<1664, blk, 0, stream>>>(l0_w, l1_w, l2_w, l3_w, l4_w,
                                        sty0, sty1, sty2, sty3, sty4,
                                        dm0, dm1, dm2, dm3, dm4);
    pack_all<<<4392, blk, 0, stream>>>(l0_w, l1_w, l2_w, l3_w, l4_w, wbase);

    // composite (NCHW -> channel-last, x sty0) -> X0
    composite_cl_kernel<<<512, blk, 0, stream>>>(fg, mask, bg, sty0, X0);

    // l0: conv 256->128 @32, MT=2, split-K=2 -> Pbuf; combine (x sty1) -> Y0
    conv3x3_cl<0><<<dim3(4, 8, 16), blk, 0, stream>>>(X0, wp0, nullptr, nullptr, nullptr, nullptr, nullptr, Pbuf, 256, 128, 32, 2, 4, 4);
    combine_l0_kernel<<<8192, blk, 0, stream>>>(Pbuf, dm0, l0_b, sty1, Y0);

    // l1: fused upconv+blur 128->128, 32->64, parity-split (x sty2) -> Z1
    upblur_cl<<<dim3(4, 16, 16), blk, 0, stream>>>(Y0, ew1, dm1, l1_b, sty2, Z1, 128, 128, 32, 2);

    // l2: conv 128->64 @64, MT=2 (x sty3) -> Y2
    conv3x3_cl<1><<<dim3(16, 2, 16), blk, 0, stream>>>(Z1, wp2, dm2, l2_b, sty3, nullptr, nullptr, Y2, 128, 64, 64, 4, 4, 2);

    // l3: fused upconv+blur 64->64, 64->128, parity-split (x sty4) -> Z3
    upblur_cl<<<dim3(16, 8, 16), blk, 0, stream>>>(Y2, ew3, dm3, l3_b, sty4, Z3, 64, 64, 64, 4);

    // l4: conv 64->32 @128 + fused final 1x1 (x styf/sqrt32) -> d_out
    conv3x3_cl<3><<<dim3(64, 1, 16), blk, 0, stream>>>(Z3, wp4, dm4, l4_b, styf, fin_w, obias, (float*)d_out, 64, 32, 128, 8, 2, 1);
}